// Round 7
// baseline (430.741 us; speedup 1.0000x reference)
//
#include <hip/hip_runtime.h>

// Problem constants
#define BN    2400   // B*N
#define NG    4      // groups
#define DIM   256

// R18: R17 + full register prefetch at entry (T14), launch_bounds(256,5).
// R17's VGPR=32 showed the compiler sank all global loads to point-of-use
// (bounds(256,8) left no registers) -> each phase ate a full VMEM wait.
// Now all operands (feats/M/S/V/Q/kw/kb) are loaded into named registers at
// kernel entry (~56 VGPRs), body consumes registers + LDS transposes only.
// One exposed memory wait per block instead of six. Everything else as R17.

typedef __attribute__((ext_vector_type(8))) short bf16x8;
typedef __attribute__((ext_vector_type(4))) short bf16x4;
typedef __attribute__((ext_vector_type(4))) float f32x4;

__device__ __forceinline__ float b2f(unsigned short u) {
    union { unsigned int i; float f; } v; v.i = ((unsigned int)u) << 16; return v.f;
}
__device__ __forceinline__ unsigned short f2b(float f) {
    union { float f; unsigned int i; } v; v.f = f;
    unsigned int x = v.i;
    return (unsigned short)((x + 0x7fffu + ((x >> 16) & 1u)) >> 16);  // RNE
}

__device__ __forceinline__ void glds16(const unsigned short* g, const short* l) {
    __builtin_amdgcn_global_load_lds(
        (const __attribute__((address_space(1))) unsigned int*)(const void*)g,
        (__attribute__((address_space(3))) unsigned int*)(void*)const_cast<short*>(l),
        16, 0, 0);
}

__device__ __forceinline__ bf16x8 cvt8(const float* p) {
    float4 x0 = ((const float4*)p)[0];
    float4 x1 = ((const float4*)p)[1];
    bf16x8 v;
    v[0]=(short)f2b(x0.x); v[1]=(short)f2b(x0.y); v[2]=(short)f2b(x0.z); v[3]=(short)f2b(x0.w);
    v[4]=(short)f2b(x1.x); v[5]=(short)f2b(x1.y); v[6]=(short)f2b(x1.z); v[7]=(short)f2b(x1.w);
    return v;
}

__device__ __forceinline__ void block_stats(float s, float q, float* sRed, int tid,
                                            float inv_n, float& mean, float& istd) {
    #pragma unroll
    for (int off = 32; off > 0; off >>= 1) {
        s += __shfl_down(s, off, 64);
        q += __shfl_down(q, off, 64);
    }
    if ((tid & 63) == 0) { sRed[(tid >> 6) * 2] = s; sRed[(tid >> 6) * 2 + 1] = q; }
    __syncthreads();
    if (tid == 0) {
        float ts = 0.f, tq = 0.f;
        for (int w = 0; w < 4; ++w) { ts += sRed[2 * w]; tq += sRed[2 * w + 1]; }
        float m = ts * inv_n;
        float var = tq * inv_n - m * m;
        sRed[8] = m; sRed[9] = rsqrtf(var + 1e-5f);
    }
    __syncthreads();
    mean = sRed[8]; istd = sRed[9];
}

// single-barrier variant: leaders write partials; every thread reduces the
// 4 partial pairs itself. Caller guarantees a __syncthreads between
// consecutive calls (true in p2_fused_kernel).
__device__ __forceinline__ void block_stats2(float s, float q, float* sRed, int tid,
                                             float inv_n, float& mean, float& istd) {
    #pragma unroll
    for (int off = 32; off > 0; off >>= 1) {
        s += __shfl_down(s, off, 64);
        q += __shfl_down(q, off, 64);
    }
    if ((tid & 63) == 0) { sRed[(tid >> 6) * 2] = s; sRed[(tid >> 6) * 2 + 1] = q; }
    __syncthreads();
    float ts = 0.f, tq = 0.f;
    #pragma unroll
    for (int w = 0; w < 4; ++w) { ts += sRed[2 * w]; tq += sRed[2 * w + 1]; }
    mean = ts * inv_n;
    float var = tq * inv_n - mean * mean;
    istd = rsqrtf(var + 1e-5f);
}

// ---------------------------------------------------------------------------
// Weight preps (unchanged from R17). Output-column order n is FRAG-MAJOR.
// ---------------------------------------------------------------------------
__global__ __launch_bounds__(256) void prep_perm_kernel(
    const float* __restrict__ wA, const float* __restrict__ bA,
    unsigned short* __restrict__ oA, float* __restrict__ obA,
    const float* __restrict__ wB, const float* __restrict__ bB,
    unsigned short* __restrict__ oB, float* __restrict__ obB)
{
    const float* w = blockIdx.y ? wB : wA;
    const float* b = blockIdx.y ? bB : bA;
    unsigned short* wOut = blockIdx.y ? oB : oA;
    float* bOut = blockIdx.y ? obB : obA;

    const int n = blockIdx.x * 4 + (threadIdx.x >> 6);   // frag-major output col
    const int lane = threadIdx.x & 63;
    // decode (g,d,c) from frag-major n
    const int g = n >> 12, qq = n & 4095;
    const int chunk = qq >> 9, lf = (qq >> 3) & 63, jj = qq & 7;
    const int d = (chunk >> 1) * 16 + (lf & 15);
    const int c = (chunk & 1) * 32 + (lf >> 4) * 8 + jj;
    const int row_i = (g << 12) + c * 64 + d;            // source weight row

    const float4 x = *(const float4*)(w + (size_t)row_i * 256 + lane * 4);
    bf16x4 pk;
    pk[0] = (short)f2b(x.x); pk[1] = (short)f2b(x.y);
    pk[2] = (short)f2b(x.z); pk[3] = (short)f2b(x.w);

    const int k0 = lane * 4;
    const int nt = n >> 6, rg = (n >> 4) & 3, r16 = n & 15;
    const int kc = k0 >> 5, q = (k0 >> 3) & 3, j = k0 & 7;
    const int lp = r16 | (q << 4);
    *(bf16x4*)(wOut + ((((size_t)(nt * 8 + kc) * 4 + rg) * 64 + lp) * 8 + j)) = pk;
    if (lane == 0) bOut[n] = b[row_i];
}

__global__ __launch_bounds__(256) void prep_flat_frag_kernel(
    const float* __restrict__ a0, unsigned short* __restrict__ o0,
    const float* __restrict__ a1, unsigned short* __restrict__ o1)
{
    const float* src = blockIdx.y ? a1 : a0;
    unsigned short* dst = blockIdx.y ? o1 : o0;
    const int idx = (blockIdx.x * 256 + threadIdx.x) * 8;
    if (idx >= 4096 * 256) return;
    bf16x8 v = cvt8(src + idx);

    const int r = idx >> 8;
    const int k0 = idx & 255;
    const int g = r >> 10, o = (r >> 5) & 31, i = r & 31;
    const int n = 16384 + g * 1024 + (o >> 4) * 512
                + ((o & 15) + 16 * ((i >> 3) & 3)) * 8 + (i & 7);
    const int nt = n >> 6, rg = (n >> 4) & 3, r16 = n & 15;
    const int kc = k0 >> 5, q = (k0 >> 3) & 3;
    const int lp = r16 | (q << 4);
    *(bf16x8*)(dst + (((size_t)(nt * 8 + kc) * 4 + rg) * 64 + lp) * 8) = v;
}

__global__ __launch_bounds__(256) void prep_flat_kernel(
    const float* __restrict__ a0, unsigned short* __restrict__ o0, int n0,
    const float* __restrict__ a1, unsigned short* __restrict__ o1, int n1,
    const float* __restrict__ a2, unsigned short* __restrict__ o2, int n2)
{
    const float* src; unsigned short* dst; int n;
    if (blockIdx.y == 0)      { src = a0; dst = o0; n = n0; }
    else if (blockIdx.y == 1) { src = a1; dst = o1; n = n1; }
    else                      { src = a2; dst = o2; n = n2; }
    const int idx = (blockIdx.x * 256 + threadIdx.x) * 8;
    if (idx >= n) return;
    *(bf16x8*)(dst + idx) = cvt8(src + idx);
}

// permuted S/Q bias copy: dst[pS(r)] = src[r]
__global__ __launch_bounds__(256) void copy_bias_kernel(
    const float* __restrict__ a0, float* __restrict__ o0,
    const float* __restrict__ a1, float* __restrict__ o1)
{
    const int r = blockIdx.x * 256 + threadIdx.x;
    const int g = r >> 10, o = (r >> 5) & 31, i = r & 31;
    const int p = g * 1024 + (o >> 4) * 512
                + ((o & 15) + 16 * ((i >> 3) & 3)) * 8 + (i & 7);
    if (blockIdx.y == 0) o0[p] = a0[r]; else o1[p] = a1[r];
}

__global__ __launch_bounds__(256) void prep_pack_a_kernel(
    const float* __restrict__ qv, unsigned short* __restrict__ qvP)
{
    const int idx = blockIdx.x * 256 + threadIdx.x;   // chunk index
    if (idx >= 38 * 8 * 4 * 64) return;
    const int lane = idx & 63;
    const int rg   = (idx >> 6) & 3;
    const int kc   = (idx >> 8) & 7;
    const int mt   = idx >> 11;
    int row = mt * 64 + rg * 16 + (lane & 15);
    if (row >= BN) row = BN - 1;
    const int col = kc * 32 + (lane >> 4) * 8;
    *(bf16x8*)(qvP + (size_t)idx * 8) = cvt8(qv + (size_t)row * 256 + col);
}

// ---------------------------------------------------------------------------
// Generator GEMM (unchanged).
// ---------------------------------------------------------------------------
__global__ __launch_bounds__(256) void gemm_gen_kernel(
    const unsigned short* __restrict__ qvP,
    const unsigned short* __restrict__ W1, const float* __restrict__ b1,
    unsigned short* __restrict__ C1,
    const unsigned short* __restrict__ W2, const float* __restrict__ b2,
    unsigned short* __restrict__ C2,
    int ySplit, int M, int N)
{
    __shared__ __align__(16) char smem[33792];
    short (*sB)[16][64][8] = (short (*)[16][64][8])smem;
    short (*sC)[132]       = (short (*)[132])smem;

    const int flat = blockIdx.y * gridDim.x + blockIdx.x;
    const int nwg = gridDim.x * gridDim.y;
    const int wg = (flat & 7) * (nwg >> 3) + (flat >> 3);
    const int mb = wg % gridDim.x;
    const int nb = wg / gridDim.x;

    const bool s2 = (nb >= ySplit);
    const unsigned short* Wp = s2 ? W2 : W1;
    const float* bias = s2 ? b2 : b1;
    unsigned short* C = s2 ? C2 : C1;
    const int nbb = s2 ? nb - ySplit : nb;

    const int tid = threadIdx.x;
    const int lane = tid & 63;
    const int wave = tid >> 6;
    const int l16 = lane & 15;
    const int quad = lane >> 4;
    const int wmi = wave >> 1;
    const int wni = wave & 1;

    const int ntl = wave >> 1, kcl = wave & 1;
    const unsigned short* bSrc = Wp + (size_t)(nbb * 2 + ntl) * 16384;
    const unsigned short* aW = qvP + (size_t)(mb * 2 + wmi) * 16384;

    f32x4 acc[4][4] = {};

    #pragma unroll
    for (int r = 0; r < 4; ++r)
        glds16(bSrc + ((size_t)(0 + kcl) * 4 + r) * 512 + lane * 8,
               &sB[0][(ntl * 2 + kcl) * 4 + r][0][0]);
    __syncthreads();

    int buf = 0;
    for (int t = 0; t < 4; ++t) {
        if (t < 3) {
            #pragma unroll
            for (int r = 0; r < 4; ++r)
                glds16(bSrc + ((size_t)(2 * (t + 1) + kcl) * 4 + r) * 512 + lane * 8,
                       &sB[buf ^ 1][(ntl * 2 + kcl) * 4 + r][0][0]);
        }
        bf16x8 af[2][4];
        #pragma unroll
        for (int kci = 0; kci < 2; ++kci)
            #pragma unroll
            for (int m = 0; m < 4; ++m)
                af[kci][m] = *(const bf16x8*)(aW + ((size_t)(2 * t + kci) * 4 + m) * 512 + lane * 8);
        #pragma unroll
        for (int kci = 0; kci < 2; ++kci) {
            bf16x8 bfv[4];
            #pragma unroll
            for (int n = 0; n < 4; ++n)
                bfv[n] = *(const bf16x8*)(&sB[buf][(wni * 2 + kci) * 4 + n][lane][0]);
            #pragma unroll
            for (int m = 0; m < 4; ++m)
                #pragma unroll
                for (int n = 0; n < 4; ++n)
                    acc[m][n] = __builtin_amdgcn_mfma_f32_16x16x32_bf16(
                        af[kci][m], bfv[n], acc[m][n], 0, 0, 0);
        }
        __syncthreads();
        buf ^= 1;
    }

    #pragma unroll
    for (int n = 0; n < 4; ++n) {
        const int col = wni * 64 + n * 16 + l16;
        const float bv = bias[nbb * 128 + col];
        #pragma unroll
        for (int m = 0; m < 4; ++m) {
            const int row = wmi * 64 + m * 16 + quad * 4;
            #pragma unroll
            for (int r = 0; r < 4; ++r)
                sC[row + r][col] = (short)f2b(acc[m][n][r] + bv);
        }
    }
    __syncthreads();

    {
        const int m0 = mb * 128, n0 = nbb * 128;
        #pragma unroll
        for (int i = 0; i < 8; ++i) {
            const int row = wave * 32 + i * 4 + quad;
            const int grow = m0 + row;
            if (grow < M) {
                bf16x4 lo = *(const bf16x4*)(&sC[row][l16 * 8]);
                bf16x4 hi = *(const bf16x4*)(&sC[row][l16 * 8 + 4]);
                bf16x8 v;
                v[0]=lo[0]; v[1]=lo[1]; v[2]=lo[2]; v[3]=lo[3];
                v[4]=hi[0]; v[5]=hi[1]; v[6]=hi[2]; v[7]=hi[3];
                *(bf16x8*)(C + (size_t)grow * N + n0 + l16 * 8) = v;
            }
        }
    }
}

// ---------------------------------------------------------------------------
// Projection GEMM — LDS-staged version (unchanged).
// ---------------------------------------------------------------------------
__global__ __launch_bounds__(256) void gemm_proj_kernel(
    const unsigned short* __restrict__ A1, const unsigned short* __restrict__ W1,
    float* __restrict__ C1,
    const unsigned short* __restrict__ A2, const unsigned short* __restrict__ W2,
    float* __restrict__ C2,
    int zSplit, int M, int N, int ldK, int kLen)
{
    __shared__ short sA[64][72];
    __shared__ short sB[64][72];

    const int z = blockIdx.z;
    const bool s2 = (z >= zSplit);
    const int zi = s2 ? z - zSplit : z;
    const unsigned short* A = s2 ? A2 : A1;
    const unsigned short* W = s2 ? W2 : W1;
    float* C = (s2 ? C2 : C1) + (size_t)zi * M * N;

    const int m0 = blockIdx.x * 64;
    const int n0 = blockIdx.y * 64;
    const int tid = threadIdx.x;
    const int lane = tid & 63;
    const int wave = tid >> 6;
    const int l16 = lane & 15;
    const int quad = lane >> 4;
    const int wr = (wave >> 1) * 32;
    const int wc = (wave & 1) * 32;

    const int lr = tid >> 2;
    const int lc = (tid & 3) * 16;

    f32x4 acc[2][2] = {};

    const int kbase = zi * kLen;
    for (int k0 = kbase; k0 < kbase + kLen; k0 += 64) {
        {
            const int gr = m0 + lr;
            bf16x8 a0 = {}, a1 = {};
            if (gr < M) {
                const unsigned short* ap = A + (size_t)gr * ldK + k0 + lc;
                a0 = ((const bf16x8*)ap)[0];
                a1 = ((const bf16x8*)ap)[1];
            }
            *(bf16x8*)(&sA[lr][lc])     = a0;
            *(bf16x8*)(&sA[lr][lc + 8]) = a1;
            const unsigned short* wp = W + (size_t)(n0 + lr) * ldK + k0 + lc;
            *(bf16x8*)(&sB[lr][lc])     = ((const bf16x8*)wp)[0];
            *(bf16x8*)(&sB[lr][lc + 8]) = ((const bf16x8*)wp)[1];
        }
        __syncthreads();
        #pragma unroll
        for (int ks = 0; ks < 64; ks += 32) {
            bf16x8 a0 = *(const bf16x8*)(&sA[wr + l16][ks + quad * 8]);
            bf16x8 a1 = *(const bf16x8*)(&sA[wr + 16 + l16][ks + quad * 8]);
            bf16x8 b0 = *(const bf16x8*)(&sB[wc + l16][ks + quad * 8]);
            bf16x8 b1 = *(const bf16x8*)(&sB[wc + 16 + l16][ks + quad * 8]);
            acc[0][0] = __builtin_amdgcn_mfma_f32_16x16x32_bf16(a0, b0, acc[0][0], 0, 0, 0);
            acc[0][1] = __builtin_amdgcn_mfma_f32_16x16x32_bf16(a0, b1, acc[0][1], 0, 0, 0);
            acc[1][0] = __builtin_amdgcn_mfma_f32_16x16x32_bf16(a1, b0, acc[1][0], 0, 0, 0);
            acc[1][1] = __builtin_amdgcn_mfma_f32_16x16x32_bf16(a1, b1, acc[1][1], 0, 0, 0);
        }
        __syncthreads();
    }

    #pragma unroll
    for (int s = 0; s < 2; ++s) {
        #pragma unroll
        for (int u = 0; u < 2; ++u) {
            const int col = n0 + wc + u * 16 + l16;
            #pragma unroll
            for (int r = 0; r < 4; ++r) {
                const int row = m0 + wr + s * 16 + quad * 4 + r;
                if (row < M)
                    C[(size_t)row * N + col] = acc[s][u][r];
            }
        }
    }
}

// ===========================================================================
// Phase-2 device helpers (small-ws split kernels; frag-aware, unchanged).
// ===========================================================================
__device__ __forceinline__ void p2_stage_feats(
    const float* fp, short (*fB)[72], int tid)
{
    *(bf16x8*)(&fB[tid >> 3][(tid & 7) * 8]) = cvt8(fp + tid * 8);
}

// frag-major 64x64 tile -> LDS [d][c]
__device__ __forceinline__ void p2_stage_64x64(
    const unsigned short* mp, short (*T)[72], int tid)
{
    #pragma unroll
    for (int h = 0; h < 2; ++h) {
        const int ri = tid + h * 256;               // 0..511 runs of 8
        bf16x8 v = *(const bf16x8*)(mp + ri * 8);
        const int chunk = ri >> 6, lf = ri & 63;
        const int d = (chunk >> 1) * 16 + (lf & 15);
        const int c = (chunk & 1) * 32 + (lf >> 4) * 8;
        *(bf16x8*)(&T[d][c]) = v;
    }
}

// frag-major 32x32 tile -> LDS [o][i]
__device__ __forceinline__ void p2_stage_32x32(
    const unsigned short* sp, short (*T)[40], int tid)
{
    if (tid < 128) {
        bf16x8 v = *(const bf16x8*)(sp + tid * 8);
        const int chunk = tid >> 6, lf = tid & 63;
        const int o = chunk * 16 + (lf & 15);
        const int i = (lf >> 4) * 8;
        *(bf16x8*)(&T[o][i]) = v;
    }
}

__device__ __forceinline__ void p2_reg_body(
    short (*fB)[72], short (*Mt)[72], short (*sS)[40], short (*X1T)[40],
    float* sRed, unsigned short* outp, int tid)
{
    const int wave = tid >> 6, lane = tid & 63;
    const int l16 = lane & 15, quad = lane >> 4;

    f32x4 accA[2] = {};
    #pragma unroll
    for (int ks = 0; ks < 64; ks += 32) {
        bf16x8 b = *(const bf16x8*)(&Mt[wave * 16 + l16][ks + quad * 8]);
        #pragma unroll
        for (int mt = 0; mt < 2; ++mt) {
            bf16x8 a = *(const bf16x8*)(&fB[mt * 16 + l16][ks + quad * 8]);
            accA[mt] = __builtin_amdgcn_mfma_f32_16x16x32_bf16(a, b, accA[mt], 0, 0, 0);
        }
    }
    float ls = 0.f, lq = 0.f;
    #pragma unroll
    for (int mt = 0; mt < 2; ++mt)
        #pragma unroll
        for (int r = 0; r < 4; ++r) { float v = accA[mt][r]; ls += v; lq += v * v; }
    float mean, istd;
    block_stats(ls, lq, sRed, tid, 1.0f / 2048.0f, mean, istd);
    #pragma unroll
    for (int mt = 0; mt < 2; ++mt) {
        bf16x4 pk;
        #pragma unroll
        for (int r = 0; r < 4; ++r) {
            float y = (accA[mt][r] - mean) * istd;
            pk[r] = (short)f2b(y > 0.f ? y : 0.f);
        }
        *(bf16x4*)(&X1T[wave * 16 + l16][mt * 16 + quad * 4]) = pk;
    }
    __syncthreads();

    f32x4 accB[2] = {};
    {
        bf16x8 b = *(const bf16x8*)(&X1T[wave * 16 + l16][quad * 8]);
        #pragma unroll
        for (int mt = 0; mt < 2; ++mt) {
            bf16x8 a = *(const bf16x8*)(&sS[mt * 16 + l16][quad * 8]);
            accB[mt] = __builtin_amdgcn_mfma_f32_16x16x32_bf16(a, b, accB[mt], 0, 0, 0);
        }
    }
    ls = 0.f; lq = 0.f;
    #pragma unroll
    for (int mt = 0; mt < 2; ++mt)
        #pragma unroll
        for (int r = 0; r < 4; ++r) { float v = accB[mt][r]; ls += v; lq += v * v; }
    block_stats(ls, lq, sRed, tid, 1.0f / 2048.0f, mean, istd);

    const int d = wave * 16 + l16;
    #pragma unroll
    for (int mt = 0; mt < 2; ++mt)
        #pragma unroll
        for (int r = 0; r < 4; ++r) {
            float y = (accB[mt][r] - mean) * istd;
            outp[(mt * 16 + quad * 4 + r) * 64 + d] = f2b(y > 0.f ? y : 0.f);
        }
}

__device__ __forceinline__ void p2_cls_body(
    short (*fB)[72], short (*Vt)[72], short (*kw)[72], short (*vRM)[72],
    short (*vT)[40], short (*kT)[40], short (*sQ)[40], short (*sSC)[40],
    float* sKB, float* sRed, unsigned short* outp, int tid)
{
    const int wave = tid >> 6, lane = tid & 63;
    const int l16 = lane & 15, quad = lane >> 4;

    f32x4 accA[2] = {};
    #pragma unroll
    for (int ks = 0; ks < 64; ks += 32) {
        bf16x8 b = *(const bf16x8*)(&Vt[wave * 16 + l16][ks + quad * 8]);
        #pragma unroll
        for (int mt = 0; mt < 2; ++mt) {
            bf16x8 a = *(const bf16x8*)(&fB[mt * 16 + l16][ks + quad * 8]);
            accA[mt] = __builtin_amdgcn_mfma_f32_16x16x32_bf16(a, b, accA[mt], 0, 0, 0);
        }
    }
    float ls = 0.f, lq = 0.f;
    #pragma unroll
    for (int mt = 0; mt < 2; ++mt)
        #pragma unroll
        for (int r = 0; r < 4; ++r) { float v = accA[mt][r]; ls += v; lq += v * v; }
    float mean, istd;
    block_stats(ls, lq, sRed, tid, 1.0f / 2048.0f, mean, istd);
    {
        const int d = wave * 16 + l16;
        #pragma unroll
        for (int mt = 0; mt < 2; ++mt) {
            bf16x4 pk;
            #pragma unroll
            for (int r = 0; r < 4; ++r) {
                float y = (accA[mt][r] - mean) * istd;
                unsigned short u = f2b(y > 0.f ? y : 0.f);
                pk[r] = (short)u;
                vRM[mt * 16 + quad * 4 + r][d] = (short)u;
            }
            *(bf16x4*)(&vT[d][mt * 16 + quad * 4]) = pk;
        }
    }
    __syncthreads();

    {
        const int it = wave >> 1, pt = wave & 1;
        f32x4 accK = {};
        #pragma unroll
        for (int ks = 0; ks < 64; ks += 32) {
            bf16x8 a = *(const bf16x8*)(&kw[it * 16 + l16][ks + quad * 8]);
            bf16x8 b = *(const bf16x8*)(&vRM[pt * 16 + l16][ks + quad * 8]);
            accK = __builtin_amdgcn_mfma_f32_16x16x32_bf16(a, b, accK, 0, 0, 0);
        }
        bf16x4 pk;
        #pragma unroll
        for (int r = 0; r < 4; ++r)
            pk[r] = (short)f2b(accK[r] + sKB[it * 16 + quad * 4 + r]);
        *(bf16x4*)(&kT[pt * 16 + l16][it * 16 + quad * 4]) = pk;
    }
    __syncthreads();

    if (wave < 2) {
        f32x4 accL[2] = {};
        bf16x8 a = *(const bf16x8*)(&sQ[wave * 16 + l16][quad * 8]);
        #pragma unroll
        for (int pt = 0; pt < 2; ++pt) {
            bf16x8 b = *(const bf16x8*)(&kT[pt * 16 + l16][quad * 8]);
            accL[pt] = __builtin_amdgcn_mfma_f32_16x16x32_bf16(a, b, accL[pt], 0, 0, 0);
        }
        #pragma unroll
        for (int r = 0; r < 4; ++r) {
            float a0 = accL[0][r] * 0.125f, a1 = accL[1][r] * 0.125f;
            float mx = fmaxf(a0, a1);
            #pragma unroll
            for (int m = 1; m < 16; m <<= 1) mx = fmaxf(mx, __shfl_xor(mx, m, 64));
            a0 = __expf(a0 - mx); a1 = __expf(a1 - mx);
            float sum = a0 + a1;
            #pragma unroll
            for (int m = 1; m < 16; m <<= 1) sum += __shfl_xor(sum, m, 64);
            const float inv_s = 1.0f / sum;
            const int o = wave * 16 + quad * 4 + r;
            sSC[o][l16]      = (short)f2b(a0 * inv_s);
            sSC[o][16 + l16] = (short)f2b(a1 * inv_s);
        }
    }
    __syncthreads();

    f32x4 accB[2] = {};
    {
        bf16x8 b = *(const bf16x8*)(&vT[wave * 16 + l16][quad * 8]);
        #pragma unroll
        for (int mt = 0; mt < 2; ++mt) {
            bf16x8 a = *(const bf16x8*)(&sSC[mt * 16 + l16][quad * 8]);
            accB[mt] = __builtin_amdgcn_mfma_f32_16x16x32_bf16(a, b, accB[mt], 0, 0, 0);
        }
    }
    ls = 0.f; lq = 0.f;
    #pragma unroll
    for (int mt = 0; mt < 2; ++mt)
        #pragma unroll
        for (int r = 0; r < 4; ++r) { float v = accB[mt][r]; ls += v; lq += v * v; }
    block_stats(ls, lq, sRed, tid, 1.0f / 2048.0f, mean, istd);

    const int d = wave * 16 + l16;
    #pragma unroll
    for (int mt = 0; mt < 2; ++mt)
        #pragma unroll
        for (int r = 0; r < 4; ++r) {
            float y = (accB[mt][r] - mean) * istd;
            outp[(mt * 16 + quad * 4 + r) * 64 + d] = f2b(y > 0.f ? y : 0.f);
        }
}

__device__ __forceinline__ void p2_stage_cls(
    const unsigned short* Y2row, const float* kwp, const float* kbp, int g,
    short (*kw)[72], short (*sQ)[40], float* sKB, int tid)
{
    *(bf16x8*)(&kw[tid >> 3][(tid & 7) * 8]) = cvt8(kwp + (size_t)g * 2048 + tid * 8);
    p2_stage_32x32(Y2row + 16384 + g * 1024, sQ, tid);
    if (tid < 32) sKB[tid] = kbp[g * 32 + tid];
}

// ---------------------------------------------------------------------------
// p2 split kernels (small-ws path)
// ---------------------------------------------------------------------------
__global__ __launch_bounds__(256) void p2_reg_kernel(
    const float* __restrict__ feats, const unsigned short* __restrict__ Y1,
    unsigned short* __restrict__ FMS)
{
    const int t = blockIdx.x, g = blockIdx.y;
    const int tid = threadIdx.x;
    __shared__ short fB[32][72];
    __shared__ short Mt[64][72];
    __shared__ short sS[32][40];
    __shared__ short X1T[64][40];
    __shared__ float sRed[16];

    p2_stage_feats(feats + (size_t)(t * NG + g) * 2048, fB, tid);
    p2_stage_64x64(Y1 + (size_t)t * 20480 + g * 4096, Mt, tid);
    p2_stage_32x32(Y1 + (size_t)t * 20480 + 16384 + g * 1024, sS, tid);
    __syncthreads();
    p2_reg_body(fB, Mt, sS, X1T, sRed, FMS + (size_t)t * 8192 + g * 2048, tid);
}

__global__ __launch_bounds__(256) void p2_cls_kernel(
    const float* __restrict__ feats, const unsigned short* __restrict__ Y2,
    const float* __restrict__ kwp, const float* __restrict__ kbp,
    unsigned short* __restrict__ FC)
{
    const int t = blockIdx.x, g = blockIdx.y;
    const int tid = threadIdx.x;
    __shared__ short fB[32][72];
    __shared__ short Vt[64][72];
    __shared__ short kw[32][72];
    __shared__ short vRM[32][72];
    __shared__ short vT[64][40];
    __shared__ short kT[32][40];
    __shared__ short sQ[32][40];
    __shared__ short sSC[32][40];
    __shared__ float sKB[32];
    __shared__ float sRed[16];

    p2_stage_feats(feats + (size_t)(t * NG + g) * 2048, fB, tid);
    p2_stage_64x64(Y2 + (size_t)t * 20480 + g * 4096, Vt, tid);
    p2_stage_cls(Y2 + (size_t)t * 20480, kwp, kbp, g, kw, sQ, sKB, tid);
    __syncthreads();
    p2_cls_body(fB, Vt, kw, vRM, vT, kT, sQ, sSC, sKB, sRed,
                FC + (size_t)t * 8192 + g * 2048, tid);
}

// ---------------------------------------------------------------------------
// p2 fused kernel (big-ws path) — R18: frag-major reads + FULL register
// prefetch at entry; body consumes registers + LDS transposes only.
// ---------------------------------------------------------------------------
__global__ __launch_bounds__(256, 5) void p2_fused_kernel(
    const float* __restrict__ feats,
    const unsigned short* __restrict__ Y1,
    const unsigned short* __restrict__ Y2,
    const float* __restrict__ kwp, const float* __restrict__ kbp,
    unsigned short* __restrict__ FMS, unsigned short* __restrict__ FC)
{
    const int t = blockIdx.x, g = blockIdx.y;
    const int tid = threadIdx.x;
    const int wave = tid >> 6, lane = tid & 63;
    const int l16 = lane & 15, quad = lane >> 4;

    __shared__ short XvT[64][40];    // X1T ; then vT
    __shared__ short vRM[32][72];    // v row-major ; then softmax scores
    __shared__ short kT[32][40];
    __shared__ float sRed[16];
    short (*sSC)[72] = vRM;

    const float* fBase = feats + (size_t)(t * NG + g) * 2048;
    const unsigned short* Mbase = Y1 + (size_t)t * 20480 + g * 4096;
    const unsigned short* Sbase = Y1 + (size_t)t * 20480 + 16384 + g * 1024;
    const unsigned short* Vbase = Y2 + (size_t)t * 20480 + g * 4096;
    const unsigned short* Qbase = Y2 + (size_t)t * 20480 + 16384 + g * 1024;

    // ======== FULL PREFETCH at entry (one exposed memory wait per block) ====
    bf16x8 af[2][2];                              // feats A-frags (16 VGPR)
    #pragma unroll
    for (int mt = 0; mt < 2; ++mt)
        #pragma unroll
        for (int kc = 0; kc < 2; ++kc)
            af[mt][kc] = cvt8(fBase + (mt * 16 + l16) * 64 + kc * 32 + quad * 8);
    bf16x8 bM[2], bV[2], aS[2];                   // M/V B-frags, S A-frags
    #pragma unroll
    for (int kc = 0; kc < 2; ++kc) {
        bM[kc] = *(const bf16x8*)(Mbase + (wave * 2 + kc) * 512 + lane * 8);
        bV[kc] = *(const bf16x8*)(Vbase + (wave * 2 + kc) * 512 + lane * 8);
    }
    #pragma unroll
    for (int mt = 0; mt < 2; ++mt)
        aS[mt] = *(const bf16x8*)(Sbase + mt * 512 + lane * 8);
    // Q A-frag (only waves 0/1 use it; wave&1 keeps the read in-bounds)
    bf16x8 aQ = *(const bf16x8*)(Qbase + (wave & 1) * 512 + lane * 8);
    // kw A-frags (per-wave it = wave>>1) + kb quad
    const int it = wave >> 1, pt = wave & 1;
    bf16x8 akw[2];
    {
        const float* kwBase = kwp + (size_t)g * 2048 + (it * 16 + l16) * 64 + quad * 8;
        #pragma unroll
        for (int ks = 0; ks < 2; ++ks) akw[ks] = cvt8(kwBase + ks * 32);
    }
    const float4 kbv = *(const float4*)(kbp + g * 32 + it * 16 + quad * 4);

    unsigned short* outR = FMS + (size_t)t * 8192 + g * 2048;
    unsigned short* outC = FC  + (size_t)t * 8192 + g * 2048;
    float mean, istd, ls, lq;

    // ================= reg branch =================
    {
        f32x4 accA[2] = {};
        #pragma unroll
        for (int kc = 0; kc < 2; ++kc) {
            accA[0] = __builtin_amdgcn_mfma_f32_16x16x32_bf16(af[0][kc], bM[kc], accA[0], 0, 0, 0);
            accA[1] = __builtin_amdgcn_mfma_f32_16x16x32_bf16(af[1][kc], bM[kc], accA[1], 0, 0, 0);
        }
        ls = 0.f; lq = 0.f;
        #pragma unroll
        for (int mt = 0; mt < 2; ++mt)
            #pragma unroll
            for (int r = 0; r < 4; ++r) { float v = accA[mt][r]; ls += v; lq += v * v; }
        block_stats2(ls, lq, sRed, tid, 1.0f / 2048.0f, mean, istd);   // B1
        #pragma unroll
        for (int mt = 0; mt < 2; ++mt) {
            bf16x4 pk;
            #pragma unroll
            for (int r = 0; r < 4; ++r) {
                float y = (accA[mt][r] - mean) * istd;
                pk[r] = (short)f2b(y > 0.f ? y : 0.f);
            }
            *(bf16x4*)(&XvT[wave * 16 + l16][mt * 16 + quad * 4]) = pk;
        }
        __syncthreads();                                                // B2

        f32x4 accB[2] = {};
        {
            bf16x8 b = *(const bf16x8*)(&XvT[wave * 16 + l16][quad * 8]);
            #pragma unroll
            for (int mt = 0; mt < 2; ++mt)
                accB[mt] = __builtin_amdgcn_mfma_f32_16x16x32_bf16(aS[mt], b, accB[mt], 0, 0, 0);
        }
        ls = 0.f; lq = 0.f;
        #pragma unroll
        for (int mt = 0; mt < 2; ++mt)
            #pragma unroll
            for (int r = 0; r < 4; ++r) { float v = accB[mt][r]; ls += v; lq += v * v; }
        block_stats2(ls, lq, sRed, tid, 1.0f / 2048.0f, mean, istd);   // B3

        const int d = wave * 16 + l16;
        #pragma unroll
        for (int mt = 0; mt < 2; ++mt)
            #pragma unroll
            for (int r = 0; r < 4; ++r) {
                float y = (accB[mt][r] - mean) * istd;
                outR[(mt * 16 + quad * 4 + r) * 64 + d] = f2b(y > 0.f ? y : 0.f);
            }
    }
    __syncthreads();                                                    // B4

    // ================= cls branch =================
    {
        f32x4 accA[2] = {};
        #pragma unroll
        for (int kc = 0; kc < 2; ++kc) {
            accA[0] = __builtin_amdgcn_mfma_f32_16x16x32_bf16(af[0][kc], bV[kc], accA[0], 0, 0, 0);
            accA[1] = __builtin_amdgcn_mfma_f32_16x16x32_bf16(af[1][kc], bV[kc], accA[1], 0, 0, 0);
        }
        ls = 0.f; lq = 0.f;
        #pragma unroll
        for (int mt = 0; mt < 2; ++mt)
            #pragma unroll
            for (int r = 0; r < 4; ++r) { float v = accA[mt][r]; ls += v; lq += v * v; }
        block_stats2(ls, lq, sRed, tid, 1.0f / 2048.0f, mean, istd);   // B5
        {
            const int d = wave * 16 + l16;
            #pragma unroll
            for (int mt = 0; mt < 2; ++mt) {
                bf16x4 pk;
                #pragma unroll
                for (int r = 0; r < 4; ++r) {
                    float y = (accA[mt][r] - mean) * istd;
                    unsigned short u = f2b(y > 0.f ? y : 0.f);
                    pk[r] = (short)u;
                    vRM[mt * 16 + quad * 4 + r][d] = (short)u;
                }
                *(bf16x4*)(&XvT[d][mt * 16 + quad * 4]) = pk;   // vT
            }
        }
        __syncthreads();                                                // B6

        {   // k[i][p] = kw[i]·v[p] + kb (kw from prefetched regs)
            f32x4 accK = {};
            #pragma unroll
            for (int ks = 0; ks < 2; ++ks) {
                bf16x8 b = *(const bf16x8*)(&vRM[pt * 16 + l16][ks * 32 + quad * 8]);
                accK = __builtin_amdgcn_mfma_f32_16x16x32_bf16(akw[ks], b, accK, 0, 0, 0);
            }
            bf16x4 pk;
            pk[0] = (short)f2b(accK[0] + kbv.x);
            pk[1] = (short)f2b(accK[1] + kbv.y);
            pk[2] = (short)f2b(accK[2] + kbv.z);
            pk[3] = (short)f2b(accK[3] + kbv.w);
            *(bf16x4*)(&kT[pt * 16 + l16][it * 16 + quad * 4]) = pk;
        }
        __syncthreads();                                                // B7
        // vRM dead; sSC alias becomes live

        if (wave < 2) {   // logits + softmax (Q from prefetched regs)
            f32x4 accL[2] = {};
            #pragma unroll
            for (int ptt = 0; ptt < 2; ++ptt) {
                bf16x8 b = *(const bf16x8*)(&kT[ptt * 16 + l16][quad * 8]);
                accL[ptt] = __builtin_amdgcn_mfma_f32_16x16x32_bf16(aQ, b, accL[ptt], 0, 0, 0);
            }
            #pragma unroll
            for (int r = 0; r < 4; ++r) {
                float a0 = accL[0][r] * 0.125f, a1 = accL[1][r] * 0.125f;
                float mx = fmaxf(a0, a1);
                #pragma unroll
                for (int m = 1; m < 16; m <<= 1) mx = fmaxf(mx, __shfl_xor(mx, m, 64));
                a0 = __expf(a0 - mx); a1 = __expf(a1 - mx);
                float sum = a0 + a1;
                #pragma unroll
                for (int m = 1; m < 16; m <<= 1) sum += __shfl_xor(sum, m, 64);
                const float inv_s = 1.0f / sum;
                const int o = wave * 16 + quad * 4 + r;
                sSC[o][l16]      = (short)f2b(a0 * inv_s);
                sSC[o][16 + l16] = (short)f2b(a1 * inv_s);
            }
        }
        __syncthreads();                                                // B8

        f32x4 accB[2] = {};
        {
            bf16x8 b = *(const bf16x8*)(&XvT[wave * 16 + l16][quad * 8]);
            #pragma unroll
            for (int mt = 0; mt < 2; ++mt) {
                bf16x8 a = *(const bf16x8*)(&sSC[mt * 16 + l16][quad * 8]);
                accB[mt] = __builtin_amdgcn_mfma_f32_16x16x32_bf16(a, b, accB[mt], 0, 0, 0);
            }
        }
        ls = 0.f; lq = 0.f;
        #pragma unroll
        for (int mt = 0; mt < 2; ++mt)
            #pragma unroll
            for (int r = 0; r < 4; ++r) { float v = accB[mt][r]; ls += v; lq += v * v; }
        block_stats2(ls, lq, sRed, tid, 1.0f / 2048.0f, mean, istd);   // B9

        const int d = wave * 16 + l16;
        #pragma unroll
        for (int mt = 0; mt < 2; ++mt)
            #pragma unroll
            for (int r = 0; r < 4; ++r) {
                float y = (accB[mt][r] - mean) * istd;
                outC[(mt * 16 + quad * 4 + r) * 64 + d] = f2b(y > 0.f ? y : 0.f);
            }
    }
}

// ---------------------------------------------------------------------------
// Final: reduce split-K=8 partials, residual add, affine LN over 256, fp32 out.
// ---------------------------------------------------------------------------
__global__ __launch_bounds__(256) void final_ln_kernel(
    const float* __restrict__ qv,
    const float* __restrict__ MSP, const float* __restrict__ CLP,
    const float* __restrict__ Wv_b, const float* __restrict__ Wv2_b,
    const float* __restrict__ lnA_w, const float* __restrict__ lnA_b,
    const float* __restrict__ lnB_w, const float* __restrict__ lnB_b,
    float* __restrict__ out)
{
    __shared__ float sRed[16];
    const int t = blockIdx.x;
    const int br = blockIdx.y;
    const int c = threadIdx.x;
    const float* P = br ? CLP : MSP;
    const float* bias = br ? Wv2_b : Wv_b;
    const float* lw = br ? lnB_w : lnA_w;
    const float* lb = br ? lnB_b : lnA_b;

    float x = qv[t * 256 + c] + bias[c];
    #pragma unroll
    for (int s = 0; s < 8; ++s) x += P[(size_t)s * (BN * 256) + t * 256 + c];

    float mean, istd;
    block_stats(x, x * x, sRed, c, 1.0f / 256.0f, mean, istd);
    out[(size_t)br * (BN * 256) + t * 256 + c] = (x - mean) * istd * lw[c] + lb[c];
}

// ---------------------------------------------------------------------------
extern "C" void kernel_launch(void* const* d_in, const int* in_sizes, int n_in,
                              void* d_out, int out_size, void* d_ws, size_t ws_size,
                              hipStream_t stream) {
    const float* feats = (const float*)d_in[0];
    const float* qv    = (const float*)d_in[1];
    const float* m_w   = (const float*)d_in[7];
    const float* m_b   = (const float*)d_in[8];
    const float* s_w   = (const float*)d_in[9];
    const float* s_b   = (const float*)d_in[10];
    const float* q_w   = (const float*)d_in[11];
    const float* q_b   = (const float*)d_in[12];
    const float* v_w   = (const float*)d_in[13];
    const float* v_b   = (const float*)d_in[14];
    const float* k_w   = (const float*)d_in[15];
    const float* k_b   = (const float*)d_in[16];
    const float* Wv_w  = (const float*)d_in[17];
    const float* Wv_b  = (const float*)d_in[18];
    const float* Wv2_w = (const float*)d_in[19];
    const float* Wv2_b = (const float*)d_in[20];
    const float* lnA_w = (const float*)d_in[21];
    const float* lnA_b = (const float*)d_in[22];
    const float* lnB_w = (const float*)d_in[23];
    const float* lnB_b = (const float*)d_in[24];

    char* ws = (char*)d_ws;
    const dim3 blk(256);

    if (ws_size >= 275251200ull) {
        // ===== BIG path (275.3 MB) =====
        unsigned short* Y1 = (unsigned short*)(ws);
        unsigned short* Y2 = (unsigned short*)(ws + 98304000);
        unsigned short* W1   = (unsigned short*)(ws + 196608000);
        unsigned short* W2   = (unsigned short*)(ws + 196608000 + 10485760);
        unsigned short* qvP  = (unsigned short*)(ws + 196608000 + 20971520);
        float* b1 = (float*)(ws + 196608000 + 22216704);
        float* b2 = (float*)(ws + 196608000 + 22298624);
        unsigned short* FMS = (unsigned short*)(ws + 196608000);
        unsigned short* FC  = (unsigned short*)(ws + 235929600);
        unsigned short* WvB  = (unsigned short*)(ws + 98304000);
        unsigned short* Wv2B = (unsigned short*)(ws + 98304000 + 4194304);
        float* MSP = (float*)(ws);
        float* CLP = (float*)(ws + 19660800);

        prep_perm_kernel<<<dim3(4096, 2), blk, 0, stream>>>(m_w, m_b, W1, b1,
                                                            v_w, v_b, W2, b2);
        prep_flat_frag_kernel<<<dim3(512, 2), blk, 0, stream>>>(s_w, W1, q_w, W2);
        prep_pack_a_kernel<<<304, blk, 0, stream>>>(qv, qvP);
        copy_bias_kernel<<<dim3(16, 2), blk, 0, stream>>>(s_b, b1 + 16384, q_b, b2 + 16384);
        gemm_gen_kernel<<<dim3(19, 320), blk, 0, stream>>>(
            qvP, W1, b1, Y1, W2, b2, Y2, 160, BN, 20480);
        p2_fused_kernel<<<dim3(BN, NG), blk, 0, stream>>>(
            feats, Y1, Y2, k_w, k_b, FMS, FC);
        prep_flat_kernel<<<dim3(1024, 2), blk, 0, stream>>>(
            Wv_w, WvB, 256 * 8192, Wv2_w, Wv2B, 256 * 8192, nullptr, nullptr, 0);
        gemm_proj_kernel<<<dim3(38, 4, 16), blk, 0, stream>>>(
            FMS, WvB, MSP, FC, Wv2B, CLP, 8, BN, 256, 8192, 1024);
        final_ln_kernel<<<dim3(BN, 2), blk, 0, stream>>>(
            qv, MSP, CLP, Wv_b, Wv2_b, lnA_w, lnA_b, lnB_w, lnB_b, (float*)d_out);
    } else {
        // ===== SMALL path (176.9 MB fallback) =====
        unsigned short* Y1  = (unsigned short*)(ws);
        unsigned short* FMS = (unsigned short*)(ws + 98304000);
        unsigned short* FC  = (unsigned short*)(ws + 137625600);
        unsigned short* W1   = (unsigned short*)(ws + 137625600);
        unsigned short* W2   = (unsigned short*)(ws + 137625600 + 10485760);
        unsigned short* qvP  = (unsigned short*)(ws + 137625600 + 20971520);
        float* b1 = (float*)(ws + 137625600 + 22216704);
        float* b2 = (float*)(ws + 137625600 + 22298624);
        float* MSP = (float*)(ws);
        float* CLP = (float*)(ws + 19660800);
        unsigned short* WvB  = (unsigned short*)(ws + 39321600);
        unsigned short* Wv2B = (unsigned short*)(ws + 43515904);

        prep_perm_kernel<<<dim3(4096, 2), blk, 0, stream>>>(m_w, m_b, W1, b1,
                                                            v_w, v_b, W2, b2);
        prep_flat_frag_kernel<<<dim3(512, 2), blk, 0, stream>>>(s_w, W1, q_w, W2);
        prep_pack_a_kernel<<<304, blk, 0, stream>>>(qv, qvP);
        copy_bias_kernel<<<dim3(16, 2), blk, 0, stream>>>(s_b, b1 + 16384, q_b, b2 + 16384);
        gemm_gen_kernel<<<dim3(19, 160), blk, 0, stream>>>(
            qvP, W1, b1, Y1, W1, b1, Y1, 160, BN, 20480);
        p2_reg_kernel<<<dim3(BN, NG), blk, 0, stream>>>(feats, Y1, FMS);
        gemm_gen_kernel<<<dim3(19, 160), blk, 0, stream>>>(
            qvP, W2, b2, Y1, W2, b2, Y1, 160, BN, 20480);
        p2_cls_kernel<<<dim3(BN, NG), blk, 0, stream>>>(feats, Y1, k_w, k_b, FC);
        prep_flat_kernel<<<dim3(1024, 2), blk, 0, stream>>>(
            Wv_w, WvB, 256 * 8192, Wv2_w, Wv2B, 256 * 8192, nullptr, nullptr, 0);
        gemm_proj_kernel<<<dim3(38, 4, 8), blk, 0, stream>>>(
            FMS, WvB, MSP, FMS, WvB, MSP, 8, BN, 256, 8192, 1024);
        gemm_proj_kernel<<<dim3(38, 4, 8), blk, 0, stream>>>(
            FC, Wv2B, CLP, FC, Wv2B, CLP, 8, BN, 256, 8192, 1024);
        final_ln_kernel<<<dim3(BN, 2), blk, 0, stream>>>(
            qv, MSP, CLP, Wv_b, Wv2_b, lnA_w, lnA_b, lnB_w, lnB_b, (float*)d_out);
    }
}

// Round 8
// 419.073 us; speedup vs baseline: 1.0278x; 1.0278x over previous
//
#include <hip/hip_runtime.h>

// Problem constants
#define BN    2400   // B*N
#define NG    4      // groups
#define DIM   256

// R19: p2_fused = R14's proven skeleton (prefetch anchored by immediate LDS
// staging -> compiler cannot sink the loads; 10 barriers; block_stats2)
// + frag-major Y (linear staging loads, frag-decode writes)
// + feats A-frags in registers (first use = first MFMA, no sink risk)
//   -> fB LDS deleted: 28.9 -> 24.3KB, launch_bounds(256,6), kw stages into
//   MtVt rows 0-31. R15-R18 lesson: register-resident prefetch is not
//   schedule-stable; LDS-anchored prefetch is. gen/proj/preps/final as R18.

typedef __attribute__((ext_vector_type(8))) short bf16x8;
typedef __attribute__((ext_vector_type(4))) short bf16x4;
typedef __attribute__((ext_vector_type(4))) float f32x4;

__device__ __forceinline__ float b2f(unsigned short u) {
    union { unsigned int i; float f; } v; v.i = ((unsigned int)u) << 16; return v.f;
}
__device__ __forceinline__ unsigned short f2b(float f) {
    union { float f; unsigned int i; } v; v.f = f;
    unsigned int x = v.i;
    return (unsigned short)((x + 0x7fffu + ((x >> 16) & 1u)) >> 16);  // RNE
}

__device__ __forceinline__ void glds16(const unsigned short* g, const short* l) {
    __builtin_amdgcn_global_load_lds(
        (const __attribute__((address_space(1))) unsigned int*)(const void*)g,
        (__attribute__((address_space(3))) unsigned int*)(void*)const_cast<short*>(l),
        16, 0, 0);
}

__device__ __forceinline__ bf16x8 cvt8(const float* p) {
    float4 x0 = ((const float4*)p)[0];
    float4 x1 = ((const float4*)p)[1];
    bf16x8 v;
    v[0]=(short)f2b(x0.x); v[1]=(short)f2b(x0.y); v[2]=(short)f2b(x0.z); v[3]=(short)f2b(x0.w);
    v[4]=(short)f2b(x1.x); v[5]=(short)f2b(x1.y); v[6]=(short)f2b(x1.z); v[7]=(short)f2b(x1.w);
    return v;
}

__device__ __forceinline__ void block_stats(float s, float q, float* sRed, int tid,
                                            float inv_n, float& mean, float& istd) {
    #pragma unroll
    for (int off = 32; off > 0; off >>= 1) {
        s += __shfl_down(s, off, 64);
        q += __shfl_down(q, off, 64);
    }
    if ((tid & 63) == 0) { sRed[(tid >> 6) * 2] = s; sRed[(tid >> 6) * 2 + 1] = q; }
    __syncthreads();
    if (tid == 0) {
        float ts = 0.f, tq = 0.f;
        for (int w = 0; w < 4; ++w) { ts += sRed[2 * w]; tq += sRed[2 * w + 1]; }
        float m = ts * inv_n;
        float var = tq * inv_n - m * m;
        sRed[8] = m; sRed[9] = rsqrtf(var + 1e-5f);
    }
    __syncthreads();
    mean = sRed[8]; istd = sRed[9];
}

// single-barrier variant: leaders write partials; every thread reduces the
// 4 partial pairs itself. Caller guarantees a __syncthreads between
// consecutive calls (true in p2_fused_kernel).
__device__ __forceinline__ void block_stats2(float s, float q, float* sRed, int tid,
                                             float inv_n, float& mean, float& istd) {
    #pragma unroll
    for (int off = 32; off > 0; off >>= 1) {
        s += __shfl_down(s, off, 64);
        q += __shfl_down(q, off, 64);
    }
    if ((tid & 63) == 0) { sRed[(tid >> 6) * 2] = s; sRed[(tid >> 6) * 2 + 1] = q; }
    __syncthreads();
    float ts = 0.f, tq = 0.f;
    #pragma unroll
    for (int w = 0; w < 4; ++w) { ts += sRed[2 * w]; tq += sRed[2 * w + 1]; }
    mean = ts * inv_n;
    float var = tq * inv_n - mean * mean;
    istd = rsqrtf(var + 1e-5f);
}

// ---------------------------------------------------------------------------
// Weight preps (unchanged from R17). Output-column order n is FRAG-MAJOR.
// ---------------------------------------------------------------------------
__global__ __launch_bounds__(256) void prep_perm_kernel(
    const float* __restrict__ wA, const float* __restrict__ bA,
    unsigned short* __restrict__ oA, float* __restrict__ obA,
    const float* __restrict__ wB, const float* __restrict__ bB,
    unsigned short* __restrict__ oB, float* __restrict__ obB)
{
    const float* w = blockIdx.y ? wB : wA;
    const float* b = blockIdx.y ? bB : bA;
    unsigned short* wOut = blockIdx.y ? oB : oA;
    float* bOut = blockIdx.y ? obB : obA;

    const int n = blockIdx.x * 4 + (threadIdx.x >> 6);   // frag-major output col
    const int lane = threadIdx.x & 63;
    // decode (g,d,c) from frag-major n
    const int g = n >> 12, qq = n & 4095;
    const int chunk = qq >> 9, lf = (qq >> 3) & 63, jj = qq & 7;
    const int d = (chunk >> 1) * 16 + (lf & 15);
    const int c = (chunk & 1) * 32 + (lf >> 4) * 8 + jj;
    const int row_i = (g << 12) + c * 64 + d;            // source weight row

    const float4 x = *(const float4*)(w + (size_t)row_i * 256 + lane * 4);
    bf16x4 pk;
    pk[0] = (short)f2b(x.x); pk[1] = (short)f2b(x.y);
    pk[2] = (short)f2b(x.z); pk[3] = (short)f2b(x.w);

    const int k0 = lane * 4;
    const int nt = n >> 6, rg = (n >> 4) & 3, r16 = n & 15;
    const int kc = k0 >> 5, q = (k0 >> 3) & 3, j = k0 & 7;
    const int lp = r16 | (q << 4);
    *(bf16x4*)(wOut + ((((size_t)(nt * 8 + kc) * 4 + rg) * 64 + lp) * 8 + j)) = pk;
    if (lane == 0) bOut[n] = b[row_i];
}

__global__ __launch_bounds__(256) void prep_flat_frag_kernel(
    const float* __restrict__ a0, unsigned short* __restrict__ o0,
    const float* __restrict__ a1, unsigned short* __restrict__ o1)
{
    const float* src = blockIdx.y ? a1 : a0;
    unsigned short* dst = blockIdx.y ? o1 : o0;
    const int idx = (blockIdx.x * 256 + threadIdx.x) * 8;
    if (idx >= 4096 * 256) return;
    bf16x8 v = cvt8(src + idx);

    const int r = idx >> 8;
    const int k0 = idx & 255;
    const int g = r >> 10, o = (r >> 5) & 31, i = r & 31;
    const int n = 16384 + g * 1024 + (o >> 4) * 512
                + ((o & 15) + 16 * ((i >> 3) & 3)) * 8 + (i & 7);
    const int nt = n >> 6, rg = (n >> 4) & 3, r16 = n & 15;
    const int kc = k0 >> 5, q = (k0 >> 3) & 3;
    const int lp = r16 | (q << 4);
    *(bf16x8*)(dst + (((size_t)(nt * 8 + kc) * 4 + rg) * 64 + lp) * 8) = v;
}

__global__ __launch_bounds__(256) void prep_flat_kernel(
    const float* __restrict__ a0, unsigned short* __restrict__ o0, int n0,
    const float* __restrict__ a1, unsigned short* __restrict__ o1, int n1,
    const float* __restrict__ a2, unsigned short* __restrict__ o2, int n2)
{
    const float* src; unsigned short* dst; int n;
    if (blockIdx.y == 0)      { src = a0; dst = o0; n = n0; }
    else if (blockIdx.y == 1) { src = a1; dst = o1; n = n1; }
    else                      { src = a2; dst = o2; n = n2; }
    const int idx = (blockIdx.x * 256 + threadIdx.x) * 8;
    if (idx >= n) return;
    *(bf16x8*)(dst + idx) = cvt8(src + idx);
}

// permuted S/Q bias copy: dst[pS(r)] = src[r]
__global__ __launch_bounds__(256) void copy_bias_kernel(
    const float* __restrict__ a0, float* __restrict__ o0,
    const float* __restrict__ a1, float* __restrict__ o1)
{
    const int r = blockIdx.x * 256 + threadIdx.x;
    const int g = r >> 10, o = (r >> 5) & 31, i = r & 31;
    const int p = g * 1024 + (o >> 4) * 512
                + ((o & 15) + 16 * ((i >> 3) & 3)) * 8 + (i & 7);
    if (blockIdx.y == 0) o0[p] = a0[r]; else o1[p] = a1[r];
}

__global__ __launch_bounds__(256) void prep_pack_a_kernel(
    const float* __restrict__ qv, unsigned short* __restrict__ qvP)
{
    const int idx = blockIdx.x * 256 + threadIdx.x;   // chunk index
    if (idx >= 38 * 8 * 4 * 64) return;
    const int lane = idx & 63;
    const int rg   = (idx >> 6) & 3;
    const int kc   = (idx >> 8) & 7;
    const int mt   = idx >> 11;
    int row = mt * 64 + rg * 16 + (lane & 15);
    if (row >= BN) row = BN - 1;
    const int col = kc * 32 + (lane >> 4) * 8;
    *(bf16x8*)(qvP + (size_t)idx * 8) = cvt8(qv + (size_t)row * 256 + col);
}

// ---------------------------------------------------------------------------
// Generator GEMM (unchanged).
// ---------------------------------------------------------------------------
__global__ __launch_bounds__(256) void gemm_gen_kernel(
    const unsigned short* __restrict__ qvP,
    const unsigned short* __restrict__ W1, const float* __restrict__ b1,
    unsigned short* __restrict__ C1,
    const unsigned short* __restrict__ W2, const float* __restrict__ b2,
    unsigned short* __restrict__ C2,
    int ySplit, int M, int N)
{
    __shared__ __align__(16) char smem[33792];
    short (*sB)[16][64][8] = (short (*)[16][64][8])smem;
    short (*sC)[132]       = (short (*)[132])smem;

    const int flat = blockIdx.y * gridDim.x + blockIdx.x;
    const int nwg = gridDim.x * gridDim.y;
    const int wg = (flat & 7) * (nwg >> 3) + (flat >> 3);
    const int mb = wg % gridDim.x;
    const int nb = wg / gridDim.x;

    const bool s2 = (nb >= ySplit);
    const unsigned short* Wp = s2 ? W2 : W1;
    const float* bias = s2 ? b2 : b1;
    unsigned short* C = s2 ? C2 : C1;
    const int nbb = s2 ? nb - ySplit : nb;

    const int tid = threadIdx.x;
    const int lane = tid & 63;
    const int wave = tid >> 6;
    const int l16 = lane & 15;
    const int quad = lane >> 4;
    const int wmi = wave >> 1;
    const int wni = wave & 1;

    const int ntl = wave >> 1, kcl = wave & 1;
    const unsigned short* bSrc = Wp + (size_t)(nbb * 2 + ntl) * 16384;
    const unsigned short* aW = qvP + (size_t)(mb * 2 + wmi) * 16384;

    f32x4 acc[4][4] = {};

    #pragma unroll
    for (int r = 0; r < 4; ++r)
        glds16(bSrc + ((size_t)(0 + kcl) * 4 + r) * 512 + lane * 8,
               &sB[0][(ntl * 2 + kcl) * 4 + r][0][0]);
    __syncthreads();

    int buf = 0;
    for (int t = 0; t < 4; ++t) {
        if (t < 3) {
            #pragma unroll
            for (int r = 0; r < 4; ++r)
                glds16(bSrc + ((size_t)(2 * (t + 1) + kcl) * 4 + r) * 512 + lane * 8,
                       &sB[buf ^ 1][(ntl * 2 + kcl) * 4 + r][0][0]);
        }
        bf16x8 af[2][4];
        #pragma unroll
        for (int kci = 0; kci < 2; ++kci)
            #pragma unroll
            for (int m = 0; m < 4; ++m)
                af[kci][m] = *(const bf16x8*)(aW + ((size_t)(2 * t + kci) * 4 + m) * 512 + lane * 8);
        #pragma unroll
        for (int kci = 0; kci < 2; ++kci) {
            bf16x8 bfv[4];
            #pragma unroll
            for (int n = 0; n < 4; ++n)
                bfv[n] = *(const bf16x8*)(&sB[buf][(wni * 2 + kci) * 4 + n][lane][0]);
            #pragma unroll
            for (int m = 0; m < 4; ++m)
                #pragma unroll
                for (int n = 0; n < 4; ++n)
                    acc[m][n] = __builtin_amdgcn_mfma_f32_16x16x32_bf16(
                        af[kci][m], bfv[n], acc[m][n], 0, 0, 0);
        }
        __syncthreads();
        buf ^= 1;
    }

    #pragma unroll
    for (int n = 0; n < 4; ++n) {
        const int col = wni * 64 + n * 16 + l16;
        const float bv = bias[nbb * 128 + col];
        #pragma unroll
        for (int m = 0; m < 4; ++m) {
            const int row = wmi * 64 + m * 16 + quad * 4;
            #pragma unroll
            for (int r = 0; r < 4; ++r)
                sC[row + r][col] = (short)f2b(acc[m][n][r] + bv);
        }
    }
    __syncthreads();

    {
        const int m0 = mb * 128, n0 = nbb * 128;
        #pragma unroll
        for (int i = 0; i < 8; ++i) {
            const int row = wave * 32 + i * 4 + quad;
            const int grow = m0 + row;
            if (grow < M) {
                bf16x4 lo = *(const bf16x4*)(&sC[row][l16 * 8]);
                bf16x4 hi = *(const bf16x4*)(&sC[row][l16 * 8 + 4]);
                bf16x8 v;
                v[0]=lo[0]; v[1]=lo[1]; v[2]=lo[2]; v[3]=lo[3];
                v[4]=hi[0]; v[5]=hi[1]; v[6]=hi[2]; v[7]=hi[3];
                *(bf16x8*)(C + (size_t)grow * N + n0 + l16 * 8) = v;
            }
        }
    }
}

// ---------------------------------------------------------------------------
// Projection GEMM — LDS-staged version (unchanged).
// ---------------------------------------------------------------------------
__global__ __launch_bounds__(256) void gemm_proj_kernel(
    const unsigned short* __restrict__ A1, const unsigned short* __restrict__ W1,
    float* __restrict__ C1,
    const unsigned short* __restrict__ A2, const unsigned short* __restrict__ W2,
    float* __restrict__ C2,
    int zSplit, int M, int N, int ldK, int kLen)
{
    __shared__ short sA[64][72];
    __shared__ short sB[64][72];

    const int z = blockIdx.z;
    const bool s2 = (z >= zSplit);
    const int zi = s2 ? z - zSplit : z;
    const unsigned short* A = s2 ? A2 : A1;
    const unsigned short* W = s2 ? W2 : W1;
    float* C = (s2 ? C2 : C1) + (size_t)zi * M * N;

    const int m0 = blockIdx.x * 64;
    const int n0 = blockIdx.y * 64;
    const int tid = threadIdx.x;
    const int lane = tid & 63;
    const int wave = tid >> 6;
    const int l16 = lane & 15;
    const int quad = lane >> 4;
    const int wr = (wave >> 1) * 32;
    const int wc = (wave & 1) * 32;

    const int lr = tid >> 2;
    const int lc = (tid & 3) * 16;

    f32x4 acc[2][2] = {};

    const int kbase = zi * kLen;
    for (int k0 = kbase; k0 < kbase + kLen; k0 += 64) {
        {
            const int gr = m0 + lr;
            bf16x8 a0 = {}, a1 = {};
            if (gr < M) {
                const unsigned short* ap = A + (size_t)gr * ldK + k0 + lc;
                a0 = ((const bf16x8*)ap)[0];
                a1 = ((const bf16x8*)ap)[1];
            }
            *(bf16x8*)(&sA[lr][lc])     = a0;
            *(bf16x8*)(&sA[lr][lc + 8]) = a1;
            const unsigned short* wp = W + (size_t)(n0 + lr) * ldK + k0 + lc;
            *(bf16x8*)(&sB[lr][lc])     = ((const bf16x8*)wp)[0];
            *(bf16x8*)(&sB[lr][lc + 8]) = ((const bf16x8*)wp)[1];
        }
        __syncthreads();
        #pragma unroll
        for (int ks = 0; ks < 64; ks += 32) {
            bf16x8 a0 = *(const bf16x8*)(&sA[wr + l16][ks + quad * 8]);
            bf16x8 a1 = *(const bf16x8*)(&sA[wr + 16 + l16][ks + quad * 8]);
            bf16x8 b0 = *(const bf16x8*)(&sB[wc + l16][ks + quad * 8]);
            bf16x8 b1 = *(const bf16x8*)(&sB[wc + 16 + l16][ks + quad * 8]);
            acc[0][0] = __builtin_amdgcn_mfma_f32_16x16x32_bf16(a0, b0, acc[0][0], 0, 0, 0);
            acc[0][1] = __builtin_amdgcn_mfma_f32_16x16x32_bf16(a0, b1, acc[0][1], 0, 0, 0);
            acc[1][0] = __builtin_amdgcn_mfma_f32_16x16x32_bf16(a1, b0, acc[1][0], 0, 0, 0);
            acc[1][1] = __builtin_amdgcn_mfma_f32_16x16x32_bf16(a1, b1, acc[1][1], 0, 0, 0);
        }
        __syncthreads();
    }

    #pragma unroll
    for (int s = 0; s < 2; ++s) {
        #pragma unroll
        for (int u = 0; u < 2; ++u) {
            const int col = n0 + wc + u * 16 + l16;
            #pragma unroll
            for (int r = 0; r < 4; ++r) {
                const int row = m0 + wr + s * 16 + quad * 4 + r;
                if (row < M)
                    C[(size_t)row * N + col] = acc[s][u][r];
            }
        }
    }
}

// ===========================================================================
// Phase-2 device helpers (small-ws split kernels; frag-aware, unchanged).
// ===========================================================================
__device__ __forceinline__ void p2_stage_feats(
    const float* fp, short (*fB)[72], int tid)
{
    *(bf16x8*)(&fB[tid >> 3][(tid & 7) * 8]) = cvt8(fp + tid * 8);
}

// frag-major 64x64 tile -> LDS [d][c]
__device__ __forceinline__ void p2_stage_64x64(
    const unsigned short* mp, short (*T)[72], int tid)
{
    #pragma unroll
    for (int h = 0; h < 2; ++h) {
        const int ri = tid + h * 256;               // 0..511 runs of 8
        bf16x8 v = *(const bf16x8*)(mp + ri * 8);
        const int chunk = ri >> 6, lf = ri & 63;
        const int d = (chunk >> 1) * 16 + (lf & 15);
        const int c = (chunk & 1) * 32 + (lf >> 4) * 8;
        *(bf16x8*)(&T[d][c]) = v;
    }
}

// frag-major 32x32 tile -> LDS [o][i]
__device__ __forceinline__ void p2_stage_32x32(
    const unsigned short* sp, short (*T)[40], int tid)
{
    if (tid < 128) {
        bf16x8 v = *(const bf16x8*)(sp + tid * 8);
        const int chunk = tid >> 6, lf = tid & 63;
        const int o = chunk * 16 + (lf & 15);
        const int i = (lf >> 4) * 8;
        *(bf16x8*)(&T[o][i]) = v;
    }
}

__device__ __forceinline__ void p2_reg_body(
    short (*fB)[72], short (*Mt)[72], short (*sS)[40], short (*X1T)[40],
    float* sRed, unsigned short* outp, int tid)
{
    const int wave = tid >> 6, lane = tid & 63;
    const int l16 = lane & 15, quad = lane >> 4;

    f32x4 accA[2] = {};
    #pragma unroll
    for (int ks = 0; ks < 64; ks += 32) {
        bf16x8 b = *(const bf16x8*)(&Mt[wave * 16 + l16][ks + quad * 8]);
        #pragma unroll
        for (int mt = 0; mt < 2; ++mt) {
            bf16x8 a = *(const bf16x8*)(&fB[mt * 16 + l16][ks + quad * 8]);
            accA[mt] = __builtin_amdgcn_mfma_f32_16x16x32_bf16(a, b, accA[mt], 0, 0, 0);
        }
    }
    float ls = 0.f, lq = 0.f;
    #pragma unroll
    for (int mt = 0; mt < 2; ++mt)
        #pragma unroll
        for (int r = 0; r < 4; ++r) { float v = accA[mt][r]; ls += v; lq += v * v; }
    float mean, istd;
    block_stats(ls, lq, sRed, tid, 1.0f / 2048.0f, mean, istd);
    #pragma unroll
    for (int mt = 0; mt < 2; ++mt) {
        bf16x4 pk;
        #pragma unroll
        for (int r = 0; r < 4; ++r) {
            float y = (accA[mt][r] - mean) * istd;
            pk[r] = (short)f2b(y > 0.f ? y : 0.f);
        }
        *(bf16x4*)(&X1T[wave * 16 + l16][mt * 16 + quad * 4]) = pk;
    }
    __syncthreads();

    f32x4 accB[2] = {};
    {
        bf16x8 b = *(const bf16x8*)(&X1T[wave * 16 + l16][quad * 8]);
        #pragma unroll
        for (int mt = 0; mt < 2; ++mt) {
            bf16x8 a = *(const bf16x8*)(&sS[mt * 16 + l16][quad * 8]);
            accB[mt] = __builtin_amdgcn_mfma_f32_16x16x32_bf16(a, b, accB[mt], 0, 0, 0);
        }
    }
    ls = 0.f; lq = 0.f;
    #pragma unroll
    for (int mt = 0; mt < 2; ++mt)
        #pragma unroll
        for (int r = 0; r < 4; ++r) { float v = accB[mt][r]; ls += v; lq += v * v; }
    block_stats(ls, lq, sRed, tid, 1.0f / 2048.0f, mean, istd);

    const int d = wave * 16 + l16;
    #pragma unroll
    for (int mt = 0; mt < 2; ++mt)
        #pragma unroll
        for (int r = 0; r < 4; ++r) {
            float y = (accB[mt][r] - mean) * istd;
            outp[(mt * 16 + quad * 4 + r) * 64 + d] = f2b(y > 0.f ? y : 0.f);
        }
}

__device__ __forceinline__ void p2_cls_body(
    short (*fB)[72], short (*Vt)[72], short (*kw)[72], short (*vRM)[72],
    short (*vT)[40], short (*kT)[40], short (*sQ)[40], short (*sSC)[40],
    float* sKB, float* sRed, unsigned short* outp, int tid)
{
    const int wave = tid >> 6, lane = tid & 63;
    const int l16 = lane & 15, quad = lane >> 4;

    f32x4 accA[2] = {};
    #pragma unroll
    for (int ks = 0; ks < 64; ks += 32) {
        bf16x8 b = *(const bf16x8*)(&Vt[wave * 16 + l16][ks + quad * 8]);
        #pragma unroll
        for (int mt = 0; mt < 2; ++mt) {
            bf16x8 a = *(const bf16x8*)(&fB[mt * 16 + l16][ks + quad * 8]);
            accA[mt] = __builtin_amdgcn_mfma_f32_16x16x32_bf16(a, b, accA[mt], 0, 0, 0);
        }
    }
    float ls = 0.f, lq = 0.f;
    #pragma unroll
    for (int mt = 0; mt < 2; ++mt)
        #pragma unroll
        for (int r = 0; r < 4; ++r) { float v = accA[mt][r]; ls += v; lq += v * v; }
    float mean, istd;
    block_stats(ls, lq, sRed, tid, 1.0f / 2048.0f, mean, istd);
    {
        const int d = wave * 16 + l16;
        #pragma unroll
        for (int mt = 0; mt < 2; ++mt) {
            bf16x4 pk;
            #pragma unroll
            for (int r = 0; r < 4; ++r) {
                float y = (accA[mt][r] - mean) * istd;
                unsigned short u = f2b(y > 0.f ? y : 0.f);
                pk[r] = (short)u;
                vRM[mt * 16 + quad * 4 + r][d] = (short)u;
            }
            *(bf16x4*)(&vT[d][mt * 16 + quad * 4]) = pk;
        }
    }
    __syncthreads();

    {
        const int it = wave >> 1, pt = wave & 1;
        f32x4 accK = {};
        #pragma unroll
        for (int ks = 0; ks < 64; ks += 32) {
            bf16x8 a = *(const bf16x8*)(&kw[it * 16 + l16][ks + quad * 8]);
            bf16x8 b = *(const bf16x8*)(&vRM[pt * 16 + l16][ks + quad * 8]);
            accK = __builtin_amdgcn_mfma_f32_16x16x32_bf16(a, b, accK, 0, 0, 0);
        }
        bf16x4 pk;
        #pragma unroll
        for (int r = 0; r < 4; ++r)
            pk[r] = (short)f2b(accK[r] + sKB[it * 16 + quad * 4 + r]);
        *(bf16x4*)(&kT[pt * 16 + l16][it * 16 + quad * 4]) = pk;
    }
    __syncthreads();

    if (wave < 2) {
        f32x4 accL[2] = {};
        bf16x8 a = *(const bf16x8*)(&sQ[wave * 16 + l16][quad * 8]);
        #pragma unroll
        for (int pt = 0; pt < 2; ++pt) {
            bf16x8 b = *(const bf16x8*)(&kT[pt * 16 + l16][quad * 8]);
            accL[pt] = __builtin_amdgcn_mfma_f32_16x16x32_bf16(a, b, accL[pt], 0, 0, 0);
        }
        #pragma unroll
        for (int r = 0; r < 4; ++r) {
            float a0 = accL[0][r] * 0.125f, a1 = accL[1][r] * 0.125f;
            float mx = fmaxf(a0, a1);
            #pragma unroll
            for (int m = 1; m < 16; m <<= 1) mx = fmaxf(mx, __shfl_xor(mx, m, 64));
            a0 = __expf(a0 - mx); a1 = __expf(a1 - mx);
            float sum = a0 + a1;
            #pragma unroll
            for (int m = 1; m < 16; m <<= 1) sum += __shfl_xor(sum, m, 64);
            const float inv_s = 1.0f / sum;
            const int o = wave * 16 + quad * 4 + r;
            sSC[o][l16]      = (short)f2b(a0 * inv_s);
            sSC[o][16 + l16] = (short)f2b(a1 * inv_s);
        }
    }
    __syncthreads();

    f32x4 accB[2] = {};
    {
        bf16x8 b = *(const bf16x8*)(&vT[wave * 16 + l16][quad * 8]);
        #pragma unroll
        for (int mt = 0; mt < 2; ++mt) {
            bf16x8 a = *(const bf16x8*)(&sSC[mt * 16 + l16][quad * 8]);
            accB[mt] = __builtin_amdgcn_mfma_f32_16x16x32_bf16(a, b, accB[mt], 0, 0, 0);
        }
    }
    ls = 0.f; lq = 0.f;
    #pragma unroll
    for (int mt = 0; mt < 2; ++mt)
        #pragma unroll
        for (int r = 0; r < 4; ++r) { float v = accB[mt][r]; ls += v; lq += v * v; }
    block_stats(ls, lq, sRed, tid, 1.0f / 2048.0f, mean, istd);

    const int d = wave * 16 + l16;
    #pragma unroll
    for (int mt = 0; mt < 2; ++mt)
        #pragma unroll
        for (int r = 0; r < 4; ++r) {
            float y = (accB[mt][r] - mean) * istd;
            outp[(mt * 16 + quad * 4 + r) * 64 + d] = f2b(y > 0.f ? y : 0.f);
        }
}

__device__ __forceinline__ void p2_stage_cls(
    const unsigned short* Y2row, const float* kwp, const float* kbp, int g,
    short (*kw)[72], short (*sQ)[40], float* sKB, int tid)
{
    *(bf16x8*)(&kw[tid >> 3][(tid & 7) * 8]) = cvt8(kwp + (size_t)g * 2048 + tid * 8);
    p2_stage_32x32(Y2row + 16384 + g * 1024, sQ, tid);
    if (tid < 32) sKB[tid] = kbp[g * 32 + tid];
}

// ---------------------------------------------------------------------------
// p2 split kernels (small-ws path)
// ---------------------------------------------------------------------------
__global__ __launch_bounds__(256) void p2_reg_kernel(
    const float* __restrict__ feats, const unsigned short* __restrict__ Y1,
    unsigned short* __restrict__ FMS)
{
    const int t = blockIdx.x, g = blockIdx.y;
    const int tid = threadIdx.x;
    __shared__ short fB[32][72];
    __shared__ short Mt[64][72];
    __shared__ short sS[32][40];
    __shared__ short X1T[64][40];
    __shared__ float sRed[16];

    p2_stage_feats(feats + (size_t)(t * NG + g) * 2048, fB, tid);
    p2_stage_64x64(Y1 + (size_t)t * 20480 + g * 4096, Mt, tid);
    p2_stage_32x32(Y1 + (size_t)t * 20480 + 16384 + g * 1024, sS, tid);
    __syncthreads();
    p2_reg_body(fB, Mt, sS, X1T, sRed, FMS + (size_t)t * 8192 + g * 2048, tid);
}

__global__ __launch_bounds__(256) void p2_cls_kernel(
    const float* __restrict__ feats, const unsigned short* __restrict__ Y2,
    const float* __restrict__ kwp, const float* __restrict__ kbp,
    unsigned short* __restrict__ FC)
{
    const int t = blockIdx.x, g = blockIdx.y;
    const int tid = threadIdx.x;
    __shared__ short fB[32][72];
    __shared__ short Vt[64][72];
    __shared__ short kw[32][72];
    __shared__ short vRM[32][72];
    __shared__ short vT[64][40];
    __shared__ short kT[32][40];
    __shared__ short sQ[32][40];
    __shared__ short sSC[32][40];
    __shared__ float sKB[32];
    __shared__ float sRed[16];

    p2_stage_feats(feats + (size_t)(t * NG + g) * 2048, fB, tid);
    p2_stage_64x64(Y2 + (size_t)t * 20480 + g * 4096, Vt, tid);
    p2_stage_cls(Y2 + (size_t)t * 20480, kwp, kbp, g, kw, sQ, sKB, tid);
    __syncthreads();
    p2_cls_body(fB, Vt, kw, vRM, vT, kT, sQ, sSC, sKB, sRed,
                FC + (size_t)t * 8192 + g * 2048, tid);
}

// ---------------------------------------------------------------------------
// p2 fused kernel (big-ws path) — R19: R14 skeleton (LDS-anchored prefetch),
// frag-major staging, feats A-frags in registers, 24.3KB LDS, bounds(256,6).
// ---------------------------------------------------------------------------
__global__ __launch_bounds__(256, 6) void p2_fused_kernel(
    const float* __restrict__ feats,
    const unsigned short* __restrict__ Y1,
    const unsigned short* __restrict__ Y2,
    const float* __restrict__ kwp, const float* __restrict__ kbp,
    unsigned short* __restrict__ FMS, unsigned short* __restrict__ FC)
{
    const int t = blockIdx.x, g = blockIdx.y;
    const int tid = threadIdx.x;
    const int wave = tid >> 6, lane = tid & 63;
    const int l16 = lane & 15, quad = lane >> 4;

    __shared__ short MtVt[64][72];   // M ; then V ; rows 0-31 reused for kw
    __shared__ short XvT[64][40];    // X1T ; then vT
    __shared__ short sSQ[32][40];    // S ; then Q
    __shared__ short vRM[32][72];    // v row-major ; then softmax scores
    __shared__ short kT[32][40];
    __shared__ float sKB[32];
    __shared__ float sRed[16];
    short (*sSC)[72] = vRM;          // alias: scores after vRM is dead

    const float* fBase = feats + (size_t)(t * NG + g) * 2048;
    const unsigned short* Mb = Y1 + (size_t)t * 20480 + g * 4096;
    const unsigned short* Sb = Y1 + (size_t)t * 20480 + 16384 + g * 1024;
    const unsigned short* Vb = Y2 + (size_t)t * 20480 + g * 4096;
    const unsigned short* Qb = Y2 + (size_t)t * 20480 + 16384 + g * 1024;

    // ---- prefetch ALL globals at entry ----
    bf16x8 af[2][2];                       // feats A-frags (first use = 1st MFMA)
    #pragma unroll
    for (int mt = 0; mt < 2; ++mt)
        #pragma unroll
        for (int kc = 0; kc < 2; ++kc)
            af[mt][kc] = cvt8(fBase + (mt * 16 + l16) * 64 + kc * 32 + quad * 8);
    bf16x8 m0 = ((const bf16x8*)(Mb + tid * 16))[0];
    bf16x8 m1 = ((const bf16x8*)(Mb + tid * 16))[1];
    bf16x8 v0 = ((const bf16x8*)(Vb + tid * 16))[0];
    bf16x8 v1 = ((const bf16x8*)(Vb + tid * 16))[1];
    bf16x4 s0 = *(const bf16x4*)(Sb + tid * 4);
    bf16x4 q0 = *(const bf16x4*)(Qb + tid * 4);
    bf16x8 kwv = cvt8(kwp + (size_t)g * 2048 + tid * 8);
    float kbv = (tid < 32) ? kbp[g * 32 + tid] : 0.f;

    // ---- phase-1 LDS staging (anchors the M/S loads at entry) ----
    {
        const int r0 = 2 * tid, r1 = 2 * tid + 1;
        int ch = r0 >> 6, lf = r0 & 63;
        *(bf16x8*)(&MtVt[(ch >> 1) * 16 + (lf & 15)][(ch & 1) * 32 + (lf >> 4) * 8]) = m0;
        ch = r1 >> 6; lf = r1 & 63;
        *(bf16x8*)(&MtVt[(ch >> 1) * 16 + (lf & 15)][(ch & 1) * 32 + (lf >> 4) * 8]) = m1;
        const int cs = tid >> 7, lsn = (tid >> 1) & 63;
        *(bf16x4*)(&sSQ[cs * 16 + (lsn & 15)][(lsn >> 4) * 8 + (tid & 1) * 4]) = s0;
    }
    if (tid < 32) sKB[tid] = kbv;
    __syncthreads();

    unsigned short* outR = FMS + (size_t)t * 8192 + g * 2048;
    unsigned short* outC = FC  + (size_t)t * 8192 + g * 2048;
    float mean, istd, lsum, lsq;

    // ================= reg branch =================
    {
        f32x4 accA[2] = {};
        #pragma unroll
        for (int kc = 0; kc < 2; ++kc) {
            bf16x8 b = *(const bf16x8*)(&MtVt[wave * 16 + l16][kc * 32 + quad * 8]);
            accA[0] = __builtin_amdgcn_mfma_f32_16x16x32_bf16(af[0][kc], b, accA[0], 0, 0, 0);
            accA[1] = __builtin_amdgcn_mfma_f32_16x16x32_bf16(af[1][kc], b, accA[1], 0, 0, 0);
        }
        lsum = 0.f; lsq = 0.f;
        #pragma unroll
        for (int mt = 0; mt < 2; ++mt)
            #pragma unroll
            for (int r = 0; r < 4; ++r) { float v = accA[mt][r]; lsum += v; lsq += v * v; }
        block_stats2(lsum, lsq, sRed, tid, 1.0f / 2048.0f, mean, istd);  // B1
        #pragma unroll
        for (int mt = 0; mt < 2; ++mt) {
            bf16x4 pk;
            #pragma unroll
            for (int r = 0; r < 4; ++r) {
                float y = (accA[mt][r] - mean) * istd;
                pk[r] = (short)f2b(y > 0.f ? y : 0.f);
            }
            *(bf16x4*)(&XvT[wave * 16 + l16][mt * 16 + quad * 4]) = pk;
        }
        __syncthreads();                                                  // B2

        f32x4 accB[2] = {};
        {
            bf16x8 b = *(const bf16x8*)(&XvT[wave * 16 + l16][quad * 8]);
            #pragma unroll
            for (int mt = 0; mt < 2; ++mt) {
                bf16x8 a = *(const bf16x8*)(&sSQ[mt * 16 + l16][quad * 8]);
                accB[mt] = __builtin_amdgcn_mfma_f32_16x16x32_bf16(a, b, accB[mt], 0, 0, 0);
            }
        }
        lsum = 0.f; lsq = 0.f;
        #pragma unroll
        for (int mt = 0; mt < 2; ++mt)
            #pragma unroll
            for (int r = 0; r < 4; ++r) { float v = accB[mt][r]; lsum += v; lsq += v * v; }
        block_stats2(lsum, lsq, sRed, tid, 1.0f / 2048.0f, mean, istd);  // B3
        // all MtVt/sSQ reads complete by B3 -> safe to restage below
        const int d = wave * 16 + l16;
        #pragma unroll
        for (int mt = 0; mt < 2; ++mt)
            #pragma unroll
            for (int r = 0; r < 4; ++r) {
                float y = (accB[mt][r] - mean) * istd;
                outR[(mt * 16 + quad * 4 + r) * 64 + d] = f2b(y > 0.f ? y : 0.f);
            }
    }

    // ---- phase-2 LDS staging from prefetched regs (no global latency) ----
    {
        const int r0 = 2 * tid, r1 = 2 * tid + 1;
        int ch = r0 >> 6, lf = r0 & 63;
        *(bf16x8*)(&MtVt[(ch >> 1) * 16 + (lf & 15)][(ch & 1) * 32 + (lf >> 4) * 8]) = v0;
        ch = r1 >> 6; lf = r1 & 63;
        *(bf16x8*)(&MtVt[(ch >> 1) * 16 + (lf & 15)][(ch & 1) * 32 + (lf >> 4) * 8]) = v1;
        const int cs = tid >> 7, lsn = (tid >> 1) & 63;
        *(bf16x4*)(&sSQ[cs * 16 + (lsn & 15)][(lsn >> 4) * 8 + (tid & 1) * 4]) = q0;
    }
    __syncthreads();                                                      // B4

    // ================= cls branch =================
    {
        f32x4 accA[2] = {};
        #pragma unroll
        for (int kc = 0; kc < 2; ++kc) {
            bf16x8 b = *(const bf16x8*)(&MtVt[wave * 16 + l16][kc * 32 + quad * 8]);
            accA[0] = __builtin_amdgcn_mfma_f32_16x16x32_bf16(af[0][kc], b, accA[0], 0, 0, 0);
            accA[1] = __builtin_amdgcn_mfma_f32_16x16x32_bf16(af[1][kc], b, accA[1], 0, 0, 0);
        }
        lsum = 0.f; lsq = 0.f;
        #pragma unroll
        for (int mt = 0; mt < 2; ++mt)
            #pragma unroll
            for (int r = 0; r < 4; ++r) { float v = accA[mt][r]; lsum += v; lsq += v * v; }
        block_stats2(lsum, lsq, sRed, tid, 1.0f / 2048.0f, mean, istd);  // B5
        // V reads complete by B5 -> rows 0-31 of MtVt reusable for kw
        {
            const int d = wave * 16 + l16;
            #pragma unroll
            for (int mt = 0; mt < 2; ++mt) {
                bf16x4 pk;
                #pragma unroll
                for (int r = 0; r < 4; ++r) {
                    float y = (accA[mt][r] - mean) * istd;
                    unsigned short u = f2b(y > 0.f ? y : 0.f);
                    pk[r] = (short)u;
                    vRM[mt * 16 + quad * 4 + r][d] = (short)u;
                }
                *(bf16x4*)(&XvT[d][mt * 16 + quad * 4]) = pk;   // vT
            }
        }
        *(bf16x8*)(&MtVt[tid >> 3][(tid & 7) * 8]) = kwv;       // kw rows 0-31
        __syncthreads();                                                  // B6

        const int it = wave >> 1, pt = wave & 1;
        {   // k[i][p] = kw[i]·v[p] + kb
            f32x4 accK = {};
            #pragma unroll
            for (int ks = 0; ks < 64; ks += 32) {
                bf16x8 a = *(const bf16x8*)(&MtVt[it * 16 + l16][ks + quad * 8]);
                bf16x8 b = *(const bf16x8*)(&vRM[pt * 16 + l16][ks + quad * 8]);
                accK = __builtin_amdgcn_mfma_f32_16x16x32_bf16(a, b, accK, 0, 0, 0);
            }
            bf16x4 pk;
            #pragma unroll
            for (int r = 0; r < 4; ++r)
                pk[r] = (short)f2b(accK[r] + sKB[it * 16 + quad * 4 + r]);
            *(bf16x4*)(&kT[pt * 16 + l16][it * 16 + quad * 4]) = pk;
        }
        __syncthreads();                                                  // B7
        // vRM dead; sSC alias becomes live

        if (wave < 2) {   // logits + softmax (Q staged in sSQ)
            f32x4 accL[2] = {};
            bf16x8 a = *(const bf16x8*)(&sSQ[wave * 16 + l16][quad * 8]);
            #pragma unroll
            for (int ptt = 0; ptt < 2; ++ptt) {
                bf16x8 b = *(const bf16x8*)(&kT[ptt * 16 + l16][quad * 8]);
                accL[ptt] = __builtin_amdgcn_mfma_f32_16x16x32_bf16(a, b, accL[ptt], 0, 0, 0);
            }
            #pragma unroll
            for (int r = 0; r < 4; ++r) {
                float a0 = accL[0][r] * 0.125f, a1 = accL[1][r] * 0.125f;
                float mx = fmaxf(a0, a1);
                #pragma unroll
                for (int m = 1; m < 16; m <<= 1) mx = fmaxf(mx, __shfl_xor(mx, m, 64));
                a0 = __expf(a0 - mx); a1 = __expf(a1 - mx);
                float sum = a0 + a1;
                #pragma unroll
                for (int m = 1; m < 16; m <<= 1) sum += __shfl_xor(sum, m, 64);
                const float inv_s = 1.0f / sum;
                const int o = wave * 16 + quad * 4 + r;
                sSC[o][l16]      = (short)f2b(a0 * inv_s);
                sSC[o][16 + l16] = (short)f2b(a1 * inv_s);
            }
        }
        __syncthreads();                                                  // B8

        f32x4 accB[2] = {};
        {
            bf16x8 b = *(const bf16x8*)(&XvT[wave * 16 + l16][quad * 8]);
            #pragma unroll
            for (int mt = 0; mt < 2; ++mt) {
                bf16x8 a = *(const bf16x8*)(&sSC[mt * 16 + l16][quad * 8]);
                accB[mt] = __builtin_amdgcn_mfma_f32_16x16x32_bf16(a, b, accB[mt], 0, 0, 0);
            }
        }
        lsum = 0.f; lsq = 0.f;
        #pragma unroll
        for (int mt = 0; mt < 2; ++mt)
            #pragma unroll
            for (int r = 0; r < 4; ++r) { float v = accB[mt][r]; lsum += v; lsq += v * v; }
        block_stats2(lsum, lsq, sRed, tid, 1.0f / 2048.0f, mean, istd);  // B9

        const int d = wave * 16 + l16;
        #pragma unroll
        for (int mt = 0; mt < 2; ++mt)
            #pragma unroll
            for (int r = 0; r < 4; ++r) {
                float y = (accB[mt][r] - mean) * istd;
                outC[(mt * 16 + quad * 4 + r) * 64 + d] = f2b(y > 0.f ? y : 0.f);
            }
    }
}

// ---------------------------------------------------------------------------
// Final: reduce split-K=8 partials, residual add, affine LN over 256, fp32 out.
// ---------------------------------------------------------------------------
__global__ __launch_bounds__(256) void final_ln_kernel(
    const float* __restrict__ qv,
    const float* __restrict__ MSP, const float* __restrict__ CLP,
    const float* __restrict__ Wv_b, const float* __restrict__ Wv2_b,
    const float* __restrict__ lnA_w, const float* __restrict__ lnA_b,
    const float* __restrict__ lnB_w, const float* __restrict__ lnB_b,
    float* __restrict__ out)
{
    __shared__ float sRed[16];
    const int t = blockIdx.x;
    const int br = blockIdx.y;
    const int c = threadIdx.x;
    const float* P = br ? CLP : MSP;
    const float* bias = br ? Wv2_b : Wv_b;
    const float* lw = br ? lnB_w : lnA_w;
    const float* lb = br ? lnB_b : lnA_b;

    float x = qv[t * 256 + c] + bias[c];
    #pragma unroll
    for (int s = 0; s < 8; ++s) x += P[(size_t)s * (BN * 256) + t * 256 + c];

    float mean, istd;
    block_stats(x, x * x, sRed, c, 1.0f / 256.0f, mean, istd);
    out[(size_t)br * (BN * 256) + t * 256 + c] = (x - mean) * istd * lw[c] + lb[c];
}

// ---------------------------------------------------------------------------
extern "C" void kernel_launch(void* const* d_in, const int* in_sizes, int n_in,
                              void* d_out, int out_size, void* d_ws, size_t ws_size,
                              hipStream_t stream) {
    const float* feats = (const float*)d_in[0];
    const float* qv    = (const float*)d_in[1];
    const float* m_w   = (const float*)d_in[7];
    const float* m_b   = (const float*)d_in[8];
    const float* s_w   = (const float*)d_in[9];
    const float* s_b   = (const float*)d_in[10];
    const float* q_w   = (const float*)d_in[11];
    const float* q_b   = (const float*)d_in[12];
    const float* v_w   = (const float*)d_in[13];
    const float* v_b   = (const float*)d_in[14];
    const float* k_w   = (const float*)d_in[15];
    const float* k_b   = (const float*)d_in[16];
    const float* Wv_w  = (const float*)d_in[17];
    const float* Wv_b  = (const float*)d_in[18];
    const float* Wv2_w = (const float*)d_in[19];
    const float* Wv2_b = (const float*)d_in[20];
    const float* lnA_w = (const float*)d_in[21];
    const float* lnA_b = (const float*)d_in[22];
    const float* lnB_w = (const float*)d_in[23];
    const float* lnB_b = (const float*)d_in[24];

    char* ws = (char*)d_ws;
    const dim3 blk(256);

    if (ws_size >= 275251200ull) {
        // ===== BIG path (275.3 MB) =====
        unsigned short* Y1 = (unsigned short*)(ws);
        unsigned short* Y2 = (unsigned short*)(ws + 98304000);
        unsigned short* W1   = (unsigned short*)(ws + 196608000);
        unsigned short* W2   = (unsigned short*)(ws + 196608000 + 10485760);
        unsigned short* qvP  = (unsigned short*)(ws + 196608000 + 20971520);
        float* b1 = (float*)(ws + 196608000 + 22216704);
        float* b2 = (float*)(ws + 196608000 + 22298624);
        unsigned short* FMS = (unsigned short*)(ws + 196608000);
        unsigned short* FC  = (unsigned short*)(ws + 235929600);
        unsigned short* WvB  = (unsigned short*)(ws + 98304000);
        unsigned short* Wv2B = (unsigned short*)(ws + 98304000 + 4194304);
        float* MSP = (float*)(ws);
        float* CLP = (float*)(ws + 19660800);

        prep_perm_kernel<<<dim3(4096, 2), blk, 0, stream>>>(m_w, m_b, W1, b1,
                                                            v_w, v_b, W2, b2);
        prep_flat_frag_kernel<<<dim3(512, 2), blk, 0, stream>>>(s_w, W1, q_w, W2);
        prep_pack_a_kernel<<<304, blk, 0, stream>>>(qv, qvP);
        copy_bias_kernel<<<dim3(16, 2), blk, 0, stream>>>(s_b, b1 + 16384, q_b, b2 + 16384);
        gemm_gen_kernel<<<dim3(19, 320), blk, 0, stream>>>(
            qvP, W1, b1, Y1, W2, b2, Y2, 160, BN, 20480);
        p2_fused_kernel<<<dim3(BN, NG), blk, 0, stream>>>(
            feats, Y1, Y2, k_w, k_b, FMS, FC);
        prep_flat_kernel<<<dim3(1024, 2), blk, 0, stream>>>(
            Wv_w, WvB, 256 * 8192, Wv2_w, Wv2B, 256 * 8192, nullptr, nullptr, 0);
        gemm_proj_kernel<<<dim3(38, 4, 16), blk, 0, stream>>>(
            FMS, WvB, MSP, FC, Wv2B, CLP, 8, BN, 256, 8192, 1024);
        final_ln_kernel<<<dim3(BN, 2), blk, 0, stream>>>(
            qv, MSP, CLP, Wv_b, Wv2_b, lnA_w, lnA_b, lnB_w, lnB_b, (float*)d_out);
    } else {
        // ===== SMALL path (176.9 MB fallback) =====
        unsigned short* Y1  = (unsigned short*)(ws);
        unsigned short* FMS = (unsigned short*)(ws + 98304000);
        unsigned short* FC  = (unsigned short*)(ws + 137625600);
        unsigned short* W1   = (unsigned short*)(ws + 137625600);
        unsigned short* W2   = (unsigned short*)(ws + 137625600 + 10485760);
        unsigned short* qvP  = (unsigned short*)(ws + 137625600 + 20971520);
        float* b1 = (float*)(ws + 137625600 + 22216704);
        float* b2 = (float*)(ws + 137625600 + 22298624);
        float* MSP = (float*)(ws);
        float* CLP = (float*)(ws + 19660800);
        unsigned short* WvB  = (unsigned short*)(ws + 39321600);
        unsigned short* Wv2B = (unsigned short*)(ws + 43515904);

        prep_perm_kernel<<<dim3(4096, 2), blk, 0, stream>>>(m_w, m_b, W1, b1,
                                                            v_w, v_b, W2, b2);
        prep_flat_frag_kernel<<<dim3(512, 2), blk, 0, stream>>>(s_w, W1, q_w, W2);
        prep_pack_a_kernel<<<304, blk, 0, stream>>>(qv, qvP);
        copy_bias_kernel<<<dim3(16, 2), blk, 0, stream>>>(s_b, b1 + 16384, q_b, b2 + 16384);
        gemm_gen_kernel<<<dim3(19, 160), blk, 0, stream>>>(
            qvP, W1, b1, Y1, W1, b1, Y1, 160, BN, 20480);
        p2_reg_kernel<<<dim3(BN, NG), blk, 0, stream>>>(feats, Y1, FMS);
        gemm_gen_kernel<<<dim3(19, 160), blk, 0, stream>>>(
            qvP, W2, b2, Y1, W2, b2, Y1, 160, BN, 20480);
        p2_cls_kernel<<<dim3(BN, NG), blk, 0, stream>>>(feats, Y1, k_w, k_b, FC);
        prep_flat_kernel<<<dim3(1024, 2), blk, 0, stream>>>(
            Wv_w, WvB, 256 * 8192, Wv2_w, Wv2B, 256 * 8192, nullptr, nullptr, 0);
        gemm_proj_kernel<<<dim3(38, 4, 8), blk, 0, stream>>>(
            FMS, WvB, MSP, FMS, WvB, MSP, 8, BN, 256, 8192, 1024);
        gemm_proj_kernel<<<dim3(38, 4, 8), blk, 0, stream>>>(
            FC, Wv2B, CLP, FC, Wv2B, CLP, 8, BN, 256, 8192, 1024);
        final_ln_kernel<<<dim3(BN, 2), blk, 0, stream>>>(
            qv, MSP, CLP, Wv_b, Wv2_b, lnA_w, lnA_b, lnB_w, lnB_b, (float*)d_out);
    }
}

// Round 9
// 404.390 us; speedup vs baseline: 1.0652x; 1.0363x over previous
//
#include <hip/hip_runtime.h>

// Problem constants
#define BN    2400   // B*N
#define NG    4      // groups
#define DIM   256

// R20: p2_fused reverted to the EXACT R14 structure (82us proven):
//  - feats staged to fB LDS via 2 coalesced float4 loads (NOT direct frag
//    gathers - R19's 16-segment feats reads were the 96-vs-82 regression);
//  - all other operands prefetched at entry, anchored by immediate LDS
//    stores (M/S) or consumed at the mid-kernel restage (V/Q/kw);
//  - 28.9KB LDS, launch_bounds(256,5), block_stats2 single-barrier stats.
// Only delta vs R14: LDS-write decodes are frag-major-aware (Y is stored
// frag-major since R17; staging LOADS stay linear tid*16 - coalescing
// unchanged). gen/proj/preps/final unchanged from R19.

typedef __attribute__((ext_vector_type(8))) short bf16x8;
typedef __attribute__((ext_vector_type(4))) short bf16x4;
typedef __attribute__((ext_vector_type(4))) float f32x4;

__device__ __forceinline__ float b2f(unsigned short u) {
    union { unsigned int i; float f; } v; v.i = ((unsigned int)u) << 16; return v.f;
}
__device__ __forceinline__ unsigned short f2b(float f) {
    union { float f; unsigned int i; } v; v.f = f;
    unsigned int x = v.i;
    return (unsigned short)((x + 0x7fffu + ((x >> 16) & 1u)) >> 16);  // RNE
}

__device__ __forceinline__ void glds16(const unsigned short* g, const short* l) {
    __builtin_amdgcn_global_load_lds(
        (const __attribute__((address_space(1))) unsigned int*)(const void*)g,
        (__attribute__((address_space(3))) unsigned int*)(void*)const_cast<short*>(l),
        16, 0, 0);
}

__device__ __forceinline__ bf16x8 cvt8(const float* p) {
    float4 x0 = ((const float4*)p)[0];
    float4 x1 = ((const float4*)p)[1];
    bf16x8 v;
    v[0]=(short)f2b(x0.x); v[1]=(short)f2b(x0.y); v[2]=(short)f2b(x0.z); v[3]=(short)f2b(x0.w);
    v[4]=(short)f2b(x1.x); v[5]=(short)f2b(x1.y); v[6]=(short)f2b(x1.z); v[7]=(short)f2b(x1.w);
    return v;
}

__device__ __forceinline__ void block_stats(float s, float q, float* sRed, int tid,
                                            float inv_n, float& mean, float& istd) {
    #pragma unroll
    for (int off = 32; off > 0; off >>= 1) {
        s += __shfl_down(s, off, 64);
        q += __shfl_down(q, off, 64);
    }
    if ((tid & 63) == 0) { sRed[(tid >> 6) * 2] = s; sRed[(tid >> 6) * 2 + 1] = q; }
    __syncthreads();
    if (tid == 0) {
        float ts = 0.f, tq = 0.f;
        for (int w = 0; w < 4; ++w) { ts += sRed[2 * w]; tq += sRed[2 * w + 1]; }
        float m = ts * inv_n;
        float var = tq * inv_n - m * m;
        sRed[8] = m; sRed[9] = rsqrtf(var + 1e-5f);
    }
    __syncthreads();
    mean = sRed[8]; istd = sRed[9];
}

// single-barrier variant: leaders write partials; every thread reduces the
// 4 partial pairs itself. Caller guarantees a __syncthreads between
// consecutive calls (true in p2_fused_kernel).
__device__ __forceinline__ void block_stats2(float s, float q, float* sRed, int tid,
                                             float inv_n, float& mean, float& istd) {
    #pragma unroll
    for (int off = 32; off > 0; off >>= 1) {
        s += __shfl_down(s, off, 64);
        q += __shfl_down(q, off, 64);
    }
    if ((tid & 63) == 0) { sRed[(tid >> 6) * 2] = s; sRed[(tid >> 6) * 2 + 1] = q; }
    __syncthreads();
    float ts = 0.f, tq = 0.f;
    #pragma unroll
    for (int w = 0; w < 4; ++w) { ts += sRed[2 * w]; tq += sRed[2 * w + 1]; }
    mean = ts * inv_n;
    float var = tq * inv_n - mean * mean;
    istd = rsqrtf(var + 1e-5f);
}

// ---------------------------------------------------------------------------
// Weight preps (unchanged from R17). Output-column order n is FRAG-MAJOR.
// ---------------------------------------------------------------------------
__global__ __launch_bounds__(256) void prep_perm_kernel(
    const float* __restrict__ wA, const float* __restrict__ bA,
    unsigned short* __restrict__ oA, float* __restrict__ obA,
    const float* __restrict__ wB, const float* __restrict__ bB,
    unsigned short* __restrict__ oB, float* __restrict__ obB)
{
    const float* w = blockIdx.y ? wB : wA;
    const float* b = blockIdx.y ? bB : bA;
    unsigned short* wOut = blockIdx.y ? oB : oA;
    float* bOut = blockIdx.y ? obB : obA;

    const int n = blockIdx.x * 4 + (threadIdx.x >> 6);   // frag-major output col
    const int lane = threadIdx.x & 63;
    // decode (g,d,c) from frag-major n
    const int g = n >> 12, qq = n & 4095;
    const int chunk = qq >> 9, lf = (qq >> 3) & 63, jj = qq & 7;
    const int d = (chunk >> 1) * 16 + (lf & 15);
    const int c = (chunk & 1) * 32 + (lf >> 4) * 8 + jj;
    const int row_i = (g << 12) + c * 64 + d;            // source weight row

    const float4 x = *(const float4*)(w + (size_t)row_i * 256 + lane * 4);
    bf16x4 pk;
    pk[0] = (short)f2b(x.x); pk[1] = (short)f2b(x.y);
    pk[2] = (short)f2b(x.z); pk[3] = (short)f2b(x.w);

    const int k0 = lane * 4;
    const int nt = n >> 6, rg = (n >> 4) & 3, r16 = n & 15;
    const int kc = k0 >> 5, q = (k0 >> 3) & 3, j = k0 & 7;
    const int lp = r16 | (q << 4);
    *(bf16x4*)(wOut + ((((size_t)(nt * 8 + kc) * 4 + rg) * 64 + lp) * 8 + j)) = pk;
    if (lane == 0) bOut[n] = b[row_i];
}

__global__ __launch_bounds__(256) void prep_flat_frag_kernel(
    const float* __restrict__ a0, unsigned short* __restrict__ o0,
    const float* __restrict__ a1, unsigned short* __restrict__ o1)
{
    const float* src = blockIdx.y ? a1 : a0;
    unsigned short* dst = blockIdx.y ? o1 : o0;
    const int idx = (blockIdx.x * 256 + threadIdx.x) * 8;
    if (idx >= 4096 * 256) return;
    bf16x8 v = cvt8(src + idx);

    const int r = idx >> 8;
    const int k0 = idx & 255;
    const int g = r >> 10, o = (r >> 5) & 31, i = r & 31;
    const int n = 16384 + g * 1024 + (o >> 4) * 512
                + ((o & 15) + 16 * ((i >> 3) & 3)) * 8 + (i & 7);
    const int nt = n >> 6, rg = (n >> 4) & 3, r16 = n & 15;
    const int kc = k0 >> 5, q = (k0 >> 3) & 3;
    const int lp = r16 | (q << 4);
    *(bf16x8*)(dst + (((size_t)(nt * 8 + kc) * 4 + rg) * 64 + lp) * 8) = v;
}

__global__ __launch_bounds__(256) void prep_flat_kernel(
    const float* __restrict__ a0, unsigned short* __restrict__ o0, int n0,
    const float* __restrict__ a1, unsigned short* __restrict__ o1, int n1,
    const float* __restrict__ a2, unsigned short* __restrict__ o2, int n2)
{
    const float* src; unsigned short* dst; int n;
    if (blockIdx.y == 0)      { src = a0; dst = o0; n = n0; }
    else if (blockIdx.y == 1) { src = a1; dst = o1; n = n1; }
    else                      { src = a2; dst = o2; n = n2; }
    const int idx = (blockIdx.x * 256 + threadIdx.x) * 8;
    if (idx >= n) return;
    *(bf16x8*)(dst + idx) = cvt8(src + idx);
}

// permuted S/Q bias copy: dst[pS(r)] = src[r]
__global__ __launch_bounds__(256) void copy_bias_kernel(
    const float* __restrict__ a0, float* __restrict__ o0,
    const float* __restrict__ a1, float* __restrict__ o1)
{
    const int r = blockIdx.x * 256 + threadIdx.x;
    const int g = r >> 10, o = (r >> 5) & 31, i = r & 31;
    const int p = g * 1024 + (o >> 4) * 512
                + ((o & 15) + 16 * ((i >> 3) & 3)) * 8 + (i & 7);
    if (blockIdx.y == 0) o0[p] = a0[r]; else o1[p] = a1[r];
}

__global__ __launch_bounds__(256) void prep_pack_a_kernel(
    const float* __restrict__ qv, unsigned short* __restrict__ qvP)
{
    const int idx = blockIdx.x * 256 + threadIdx.x;   // chunk index
    if (idx >= 38 * 8 * 4 * 64) return;
    const int lane = idx & 63;
    const int rg   = (idx >> 6) & 3;
    const int kc   = (idx >> 8) & 7;
    const int mt   = idx >> 11;
    int row = mt * 64 + rg * 16 + (lane & 15);
    if (row >= BN) row = BN - 1;
    const int col = kc * 32 + (lane >> 4) * 8;
    *(bf16x8*)(qvP + (size_t)idx * 8) = cvt8(qv + (size_t)row * 256 + col);
}

// ---------------------------------------------------------------------------
// Generator GEMM (unchanged).
// ---------------------------------------------------------------------------
__global__ __launch_bounds__(256) void gemm_gen_kernel(
    const unsigned short* __restrict__ qvP,
    const unsigned short* __restrict__ W1, const float* __restrict__ b1,
    unsigned short* __restrict__ C1,
    const unsigned short* __restrict__ W2, const float* __restrict__ b2,
    unsigned short* __restrict__ C2,
    int ySplit, int M, int N)
{
    __shared__ __align__(16) char smem[33792];
    short (*sB)[16][64][8] = (short (*)[16][64][8])smem;
    short (*sC)[132]       = (short (*)[132])smem;

    const int flat = blockIdx.y * gridDim.x + blockIdx.x;
    const int nwg = gridDim.x * gridDim.y;
    const int wg = (flat & 7) * (nwg >> 3) + (flat >> 3);
    const int mb = wg % gridDim.x;
    const int nb = wg / gridDim.x;

    const bool s2 = (nb >= ySplit);
    const unsigned short* Wp = s2 ? W2 : W1;
    const float* bias = s2 ? b2 : b1;
    unsigned short* C = s2 ? C2 : C1;
    const int nbb = s2 ? nb - ySplit : nb;

    const int tid = threadIdx.x;
    const int lane = tid & 63;
    const int wave = tid >> 6;
    const int l16 = lane & 15;
    const int quad = lane >> 4;
    const int wmi = wave >> 1;
    const int wni = wave & 1;

    const int ntl = wave >> 1, kcl = wave & 1;
    const unsigned short* bSrc = Wp + (size_t)(nbb * 2 + ntl) * 16384;
    const unsigned short* aW = qvP + (size_t)(mb * 2 + wmi) * 16384;

    f32x4 acc[4][4] = {};

    #pragma unroll
    for (int r = 0; r < 4; ++r)
        glds16(bSrc + ((size_t)(0 + kcl) * 4 + r) * 512 + lane * 8,
               &sB[0][(ntl * 2 + kcl) * 4 + r][0][0]);
    __syncthreads();

    int buf = 0;
    for (int t = 0; t < 4; ++t) {
        if (t < 3) {
            #pragma unroll
            for (int r = 0; r < 4; ++r)
                glds16(bSrc + ((size_t)(2 * (t + 1) + kcl) * 4 + r) * 512 + lane * 8,
                       &sB[buf ^ 1][(ntl * 2 + kcl) * 4 + r][0][0]);
        }
        bf16x8 af[2][4];
        #pragma unroll
        for (int kci = 0; kci < 2; ++kci)
            #pragma unroll
            for (int m = 0; m < 4; ++m)
                af[kci][m] = *(const bf16x8*)(aW + ((size_t)(2 * t + kci) * 4 + m) * 512 + lane * 8);
        #pragma unroll
        for (int kci = 0; kci < 2; ++kci) {
            bf16x8 bfv[4];
            #pragma unroll
            for (int n = 0; n < 4; ++n)
                bfv[n] = *(const bf16x8*)(&sB[buf][(wni * 2 + kci) * 4 + n][lane][0]);
            #pragma unroll
            for (int m = 0; m < 4; ++m)
                #pragma unroll
                for (int n = 0; n < 4; ++n)
                    acc[m][n] = __builtin_amdgcn_mfma_f32_16x16x32_bf16(
                        af[kci][m], bfv[n], acc[m][n], 0, 0, 0);
        }
        __syncthreads();
        buf ^= 1;
    }

    #pragma unroll
    for (int n = 0; n < 4; ++n) {
        const int col = wni * 64 + n * 16 + l16;
        const float bv = bias[nbb * 128 + col];
        #pragma unroll
        for (int m = 0; m < 4; ++m) {
            const int row = wmi * 64 + m * 16 + quad * 4;
            #pragma unroll
            for (int r = 0; r < 4; ++r)
                sC[row + r][col] = (short)f2b(acc[m][n][r] + bv);
        }
    }
    __syncthreads();

    {
        const int m0 = mb * 128, n0 = nbb * 128;
        #pragma unroll
        for (int i = 0; i < 8; ++i) {
            const int row = wave * 32 + i * 4 + quad;
            const int grow = m0 + row;
            if (grow < M) {
                bf16x4 lo = *(const bf16x4*)(&sC[row][l16 * 8]);
                bf16x4 hi = *(const bf16x4*)(&sC[row][l16 * 8 + 4]);
                bf16x8 v;
                v[0]=lo[0]; v[1]=lo[1]; v[2]=lo[2]; v[3]=lo[3];
                v[4]=hi[0]; v[5]=hi[1]; v[6]=hi[2]; v[7]=hi[3];
                *(bf16x8*)(C + (size_t)grow * N + n0 + l16 * 8) = v;
            }
        }
    }
}

// ---------------------------------------------------------------------------
// Projection GEMM — LDS-staged version (unchanged).
// ---------------------------------------------------------------------------
__global__ __launch_bounds__(256) void gemm_proj_kernel(
    const unsigned short* __restrict__ A1, const unsigned short* __restrict__ W1,
    float* __restrict__ C1,
    const unsigned short* __restrict__ A2, const unsigned short* __restrict__ W2,
    float* __restrict__ C2,
    int zSplit, int M, int N, int ldK, int kLen)
{
    __shared__ short sA[64][72];
    __shared__ short sB[64][72];

    const int z = blockIdx.z;
    const bool s2 = (z >= zSplit);
    const int zi = s2 ? z - zSplit : z;
    const unsigned short* A = s2 ? A2 : A1;
    const unsigned short* W = s2 ? W2 : W1;
    float* C = (s2 ? C2 : C1) + (size_t)zi * M * N;

    const int m0 = blockIdx.x * 64;
    const int n0 = blockIdx.y * 64;
    const int tid = threadIdx.x;
    const int lane = tid & 63;
    const int wave = tid >> 6;
    const int l16 = lane & 15;
    const int quad = lane >> 4;
    const int wr = (wave >> 1) * 32;
    const int wc = (wave & 1) * 32;

    const int lr = tid >> 2;
    const int lc = (tid & 3) * 16;

    f32x4 acc[2][2] = {};

    const int kbase = zi * kLen;
    for (int k0 = kbase; k0 < kbase + kLen; k0 += 64) {
        {
            const int gr = m0 + lr;
            bf16x8 a0 = {}, a1 = {};
            if (gr < M) {
                const unsigned short* ap = A + (size_t)gr * ldK + k0 + lc;
                a0 = ((const bf16x8*)ap)[0];
                a1 = ((const bf16x8*)ap)[1];
            }
            *(bf16x8*)(&sA[lr][lc])     = a0;
            *(bf16x8*)(&sA[lr][lc + 8]) = a1;
            const unsigned short* wp = W + (size_t)(n0 + lr) * ldK + k0 + lc;
            *(bf16x8*)(&sB[lr][lc])     = ((const bf16x8*)wp)[0];
            *(bf16x8*)(&sB[lr][lc + 8]) = ((const bf16x8*)wp)[1];
        }
        __syncthreads();
        #pragma unroll
        for (int ks = 0; ks < 64; ks += 32) {
            bf16x8 a0 = *(const bf16x8*)(&sA[wr + l16][ks + quad * 8]);
            bf16x8 a1 = *(const bf16x8*)(&sA[wr + 16 + l16][ks + quad * 8]);
            bf16x8 b0 = *(const bf16x8*)(&sB[wc + l16][ks + quad * 8]);
            bf16x8 b1 = *(const bf16x8*)(&sB[wc + 16 + l16][ks + quad * 8]);
            acc[0][0] = __builtin_amdgcn_mfma_f32_16x16x32_bf16(a0, b0, acc[0][0], 0, 0, 0);
            acc[0][1] = __builtin_amdgcn_mfma_f32_16x16x32_bf16(a0, b1, acc[0][1], 0, 0, 0);
            acc[1][0] = __builtin_amdgcn_mfma_f32_16x16x32_bf16(a1, b0, acc[1][0], 0, 0, 0);
            acc[1][1] = __builtin_amdgcn_mfma_f32_16x16x32_bf16(a1, b1, acc[1][1], 0, 0, 0);
        }
        __syncthreads();
    }

    #pragma unroll
    for (int s = 0; s < 2; ++s) {
        #pragma unroll
        for (int u = 0; u < 2; ++u) {
            const int col = n0 + wc + u * 16 + l16;
            #pragma unroll
            for (int r = 0; r < 4; ++r) {
                const int row = m0 + wr + s * 16 + quad * 4 + r;
                if (row < M)
                    C[(size_t)row * N + col] = acc[s][u][r];
            }
        }
    }
}

// ===========================================================================
// Phase-2 device helpers (small-ws split kernels; frag-aware, unchanged).
// ===========================================================================
__device__ __forceinline__ void p2_stage_feats(
    const float* fp, short (*fB)[72], int tid)
{
    *(bf16x8*)(&fB[tid >> 3][(tid & 7) * 8]) = cvt8(fp + tid * 8);
}

// frag-major 64x64 tile -> LDS [d][c]
__device__ __forceinline__ void p2_stage_64x64(
    const unsigned short* mp, short (*T)[72], int tid)
{
    #pragma unroll
    for (int h = 0; h < 2; ++h) {
        const int ri = tid + h * 256;               // 0..511 runs of 8
        bf16x8 v = *(const bf16x8*)(mp + ri * 8);
        const int chunk = ri >> 6, lf = ri & 63;
        const int d = (chunk >> 1) * 16 + (lf & 15);
        const int c = (chunk & 1) * 32 + (lf >> 4) * 8;
        *(bf16x8*)(&T[d][c]) = v;
    }
}

// frag-major 32x32 tile -> LDS [o][i]
__device__ __forceinline__ void p2_stage_32x32(
    const unsigned short* sp, short (*T)[40], int tid)
{
    if (tid < 128) {
        bf16x8 v = *(const bf16x8*)(sp + tid * 8);
        const int chunk = tid >> 6, lf = tid & 63;
        const int o = chunk * 16 + (lf & 15);
        const int i = (lf >> 4) * 8;
        *(bf16x8*)(&T[o][i]) = v;
    }
}

__device__ __forceinline__ void p2_reg_body(
    short (*fB)[72], short (*Mt)[72], short (*sS)[40], short (*X1T)[40],
    float* sRed, unsigned short* outp, int tid)
{
    const int wave = tid >> 6, lane = tid & 63;
    const int l16 = lane & 15, quad = lane >> 4;

    f32x4 accA[2] = {};
    #pragma unroll
    for (int ks = 0; ks < 64; ks += 32) {
        bf16x8 b = *(const bf16x8*)(&Mt[wave * 16 + l16][ks + quad * 8]);
        #pragma unroll
        for (int mt = 0; mt < 2; ++mt) {
            bf16x8 a = *(const bf16x8*)(&fB[mt * 16 + l16][ks + quad * 8]);
            accA[mt] = __builtin_amdgcn_mfma_f32_16x16x32_bf16(a, b, accA[mt], 0, 0, 0);
        }
    }
    float ls = 0.f, lq = 0.f;
    #pragma unroll
    for (int mt = 0; mt < 2; ++mt)
        #pragma unroll
        for (int r = 0; r < 4; ++r) { float v = accA[mt][r]; ls += v; lq += v * v; }
    float mean, istd;
    block_stats(ls, lq, sRed, tid, 1.0f / 2048.0f, mean, istd);
    #pragma unroll
    for (int mt = 0; mt < 2; ++mt) {
        bf16x4 pk;
        #pragma unroll
        for (int r = 0; r < 4; ++r) {
            float y = (accA[mt][r] - mean) * istd;
            pk[r] = (short)f2b(y > 0.f ? y : 0.f);
        }
        *(bf16x4*)(&X1T[wave * 16 + l16][mt * 16 + quad * 4]) = pk;
    }
    __syncthreads();

    f32x4 accB[2] = {};
    {
        bf16x8 b = *(const bf16x8*)(&X1T[wave * 16 + l16][quad * 8]);
        #pragma unroll
        for (int mt = 0; mt < 2; ++mt) {
            bf16x8 a = *(const bf16x8*)(&sS[mt * 16 + l16][quad * 8]);
            accB[mt] = __builtin_amdgcn_mfma_f32_16x16x32_bf16(a, b, accB[mt], 0, 0, 0);
        }
    }
    ls = 0.f; lq = 0.f;
    #pragma unroll
    for (int mt = 0; mt < 2; ++mt)
        #pragma unroll
        for (int r = 0; r < 4; ++r) { float v = accB[mt][r]; ls += v; lq += v * v; }
    block_stats(ls, lq, sRed, tid, 1.0f / 2048.0f, mean, istd);

    const int d = wave * 16 + l16;
    #pragma unroll
    for (int mt = 0; mt < 2; ++mt)
        #pragma unroll
        for (int r = 0; r < 4; ++r) {
            float y = (accB[mt][r] - mean) * istd;
            outp[(mt * 16 + quad * 4 + r) * 64 + d] = f2b(y > 0.f ? y : 0.f);
        }
}

__device__ __forceinline__ void p2_cls_body(
    short (*fB)[72], short (*Vt)[72], short (*kw)[72], short (*vRM)[72],
    short (*vT)[40], short (*kT)[40], short (*sQ)[40], short (*sSC)[40],
    float* sKB, float* sRed, unsigned short* outp, int tid)
{
    const int wave = tid >> 6, lane = tid & 63;
    const int l16 = lane & 15, quad = lane >> 4;

    f32x4 accA[2] = {};
    #pragma unroll
    for (int ks = 0; ks < 64; ks += 32) {
        bf16x8 b = *(const bf16x8*)(&Vt[wave * 16 + l16][ks + quad * 8]);
        #pragma unroll
        for (int mt = 0; mt < 2; ++mt) {
            bf16x8 a = *(const bf16x8*)(&fB[mt * 16 + l16][ks + quad * 8]);
            accA[mt] = __builtin_amdgcn_mfma_f32_16x16x32_bf16(a, b, accA[mt], 0, 0, 0);
        }
    }
    float ls = 0.f, lq = 0.f;
    #pragma unroll
    for (int mt = 0; mt < 2; ++mt)
        #pragma unroll
        for (int r = 0; r < 4; ++r) { float v = accA[mt][r]; ls += v; lq += v * v; }
    float mean, istd;
    block_stats(ls, lq, sRed, tid, 1.0f / 2048.0f, mean, istd);
    {
        const int d = wave * 16 + l16;
        #pragma unroll
        for (int mt = 0; mt < 2; ++mt) {
            bf16x4 pk;
            #pragma unroll
            for (int r = 0; r < 4; ++r) {
                float y = (accA[mt][r] - mean) * istd;
                unsigned short u = f2b(y > 0.f ? y : 0.f);
                pk[r] = (short)u;
                vRM[mt * 16 + quad * 4 + r][d] = (short)u;
            }
            *(bf16x4*)(&vT[d][mt * 16 + quad * 4]) = pk;
        }
    }
    __syncthreads();

    {
        const int it = wave >> 1, pt = wave & 1;
        f32x4 accK = {};
        #pragma unroll
        for (int ks = 0; ks < 64; ks += 32) {
            bf16x8 a = *(const bf16x8*)(&kw[it * 16 + l16][ks + quad * 8]);
            bf16x8 b = *(const bf16x8*)(&vRM[pt * 16 + l16][ks + quad * 8]);
            accK = __builtin_amdgcn_mfma_f32_16x16x32_bf16(a, b, accK, 0, 0, 0);
        }
        bf16x4 pk;
        #pragma unroll
        for (int r = 0; r < 4; ++r)
            pk[r] = (short)f2b(accK[r] + sKB[it * 16 + quad * 4 + r]);
        *(bf16x4*)(&kT[pt * 16 + l16][it * 16 + quad * 4]) = pk;
    }
    __syncthreads();

    if (wave < 2) {
        f32x4 accL[2] = {};
        bf16x8 a = *(const bf16x8*)(&sQ[wave * 16 + l16][quad * 8]);
        #pragma unroll
        for (int pt = 0; pt < 2; ++pt) {
            bf16x8 b = *(const bf16x8*)(&kT[pt * 16 + l16][quad * 8]);
            accL[pt] = __builtin_amdgcn_mfma_f32_16x16x32_bf16(a, b, accL[pt], 0, 0, 0);
        }
        #pragma unroll
        for (int r = 0; r < 4; ++r) {
            float a0 = accL[0][r] * 0.125f, a1 = accL[1][r] * 0.125f;
            float mx = fmaxf(a0, a1);
            #pragma unroll
            for (int m = 1; m < 16; m <<= 1) mx = fmaxf(mx, __shfl_xor(mx, m, 64));
            a0 = __expf(a0 - mx); a1 = __expf(a1 - mx);
            float sum = a0 + a1;
            #pragma unroll
            for (int m = 1; m < 16; m <<= 1) sum += __shfl_xor(sum, m, 64);
            const float inv_s = 1.0f / sum;
            const int o = wave * 16 + quad * 4 + r;
            sSC[o][l16]      = (short)f2b(a0 * inv_s);
            sSC[o][16 + l16] = (short)f2b(a1 * inv_s);
        }
    }
    __syncthreads();

    f32x4 accB[2] = {};
    {
        bf16x8 b = *(const bf16x8*)(&vT[wave * 16 + l16][quad * 8]);
        #pragma unroll
        for (int mt = 0; mt < 2; ++mt) {
            bf16x8 a = *(const bf16x8*)(&sSC[mt * 16 + l16][quad * 8]);
            accB[mt] = __builtin_amdgcn_mfma_f32_16x16x32_bf16(a, b, accB[mt], 0, 0, 0);
        }
    }
    ls = 0.f; lq = 0.f;
    #pragma unroll
    for (int mt = 0; mt < 2; ++mt)
        #pragma unroll
        for (int r = 0; r < 4; ++r) { float v = accB[mt][r]; ls += v; lq += v * v; }
    block_stats(ls, lq, sRed, tid, 1.0f / 2048.0f, mean, istd);

    const int d = wave * 16 + l16;
    #pragma unroll
    for (int mt = 0; mt < 2; ++mt)
        #pragma unroll
        for (int r = 0; r < 4; ++r) {
            float y = (accB[mt][r] - mean) * istd;
            outp[(mt * 16 + quad * 4 + r) * 64 + d] = f2b(y > 0.f ? y : 0.f);
        }
}

__device__ __forceinline__ void p2_stage_cls(
    const unsigned short* Y2row, const float* kwp, const float* kbp, int g,
    short (*kw)[72], short (*sQ)[40], float* sKB, int tid)
{
    *(bf16x8*)(&kw[tid >> 3][(tid & 7) * 8]) = cvt8(kwp + (size_t)g * 2048 + tid * 8);
    p2_stage_32x32(Y2row + 16384 + g * 1024, sQ, tid);
    if (tid < 32) sKB[tid] = kbp[g * 32 + tid];
}

// ---------------------------------------------------------------------------
// p2 split kernels (small-ws path)
// ---------------------------------------------------------------------------
__global__ __launch_bounds__(256) void p2_reg_kernel(
    const float* __restrict__ feats, const unsigned short* __restrict__ Y1,
    unsigned short* __restrict__ FMS)
{
    const int t = blockIdx.x, g = blockIdx.y;
    const int tid = threadIdx.x;
    __shared__ short fB[32][72];
    __shared__ short Mt[64][72];
    __shared__ short sS[32][40];
    __shared__ short X1T[64][40];
    __shared__ float sRed[16];

    p2_stage_feats(feats + (size_t)(t * NG + g) * 2048, fB, tid);
    p2_stage_64x64(Y1 + (size_t)t * 20480 + g * 4096, Mt, tid);
    p2_stage_32x32(Y1 + (size_t)t * 20480 + 16384 + g * 1024, sS, tid);
    __syncthreads();
    p2_reg_body(fB, Mt, sS, X1T, sRed, FMS + (size_t)t * 8192 + g * 2048, tid);
}

__global__ __launch_bounds__(256) void p2_cls_kernel(
    const float* __restrict__ feats, const unsigned short* __restrict__ Y2,
    const float* __restrict__ kwp, const float* __restrict__ kbp,
    unsigned short* __restrict__ FC)
{
    const int t = blockIdx.x, g = blockIdx.y;
    const int tid = threadIdx.x;
    __shared__ short fB[32][72];
    __shared__ short Vt[64][72];
    __shared__ short kw[32][72];
    __shared__ short vRM[32][72];
    __shared__ short vT[64][40];
    __shared__ short kT[32][40];
    __shared__ short sQ[32][40];
    __shared__ short sSC[32][40];
    __shared__ float sKB[32];
    __shared__ float sRed[16];

    p2_stage_feats(feats + (size_t)(t * NG + g) * 2048, fB, tid);
    p2_stage_64x64(Y2 + (size_t)t * 20480 + g * 4096, Vt, tid);
    p2_stage_cls(Y2 + (size_t)t * 20480, kwp, kbp, g, kw, sQ, sKB, tid);
    __syncthreads();
    p2_cls_body(fB, Vt, kw, vRM, vT, kT, sQ, sSC, sKB, sRed,
                FC + (size_t)t * 8192 + g * 2048, tid);
}

// ---------------------------------------------------------------------------
// p2 fused kernel (big-ws path) — R20: exact R14 structure; frag-major-aware
// LDS-write decodes; 28.9KB LDS; launch_bounds(256,5).
// ---------------------------------------------------------------------------
__global__ __launch_bounds__(256, 5) void p2_fused_kernel(
    const float* __restrict__ feats,
    const unsigned short* __restrict__ Y1,
    const unsigned short* __restrict__ Y2,
    const float* __restrict__ kwp, const float* __restrict__ kbp,
    unsigned short* __restrict__ FMS, unsigned short* __restrict__ FC)
{
    const int t = blockIdx.x, g = blockIdx.y;
    const int tid = threadIdx.x;
    const int wave = tid >> 6, lane = tid & 63;
    const int l16 = lane & 15, quad = lane >> 4;

    __shared__ short fB[32][72];     // feats ; then kw
    __shared__ short MtVt[64][72];   // M ; then V
    __shared__ short XvT[64][40];    // X1T ; then vT
    __shared__ short sSQ[32][40];    // S ; then Q
    __shared__ short vRM[32][72];    // v row-major ; then softmax scores
    __shared__ short kT[32][40];
    __shared__ float sKB[32];
    __shared__ float sRed[16];
    short (*sSC)[72] = vRM;          // alias: scores after vRM is dead

    // ---- issue ALL global loads up-front (T14, coalesced only) ----
    const float* fp = feats + (size_t)(t * NG + g) * 2048 + tid * 8;
    float4 f0 = ((const float4*)fp)[0];
    float4 f1 = ((const float4*)fp)[1];
    const unsigned short* y1m = Y1 + (size_t)t * 20480 + g * 4096 + tid * 16;
    bf16x8 m0 = ((const bf16x8*)y1m)[0];
    bf16x8 m1 = ((const bf16x8*)y1m)[1];
    bf16x4 s0 = *(const bf16x4*)(Y1 + (size_t)t * 20480 + 16384 + g * 1024 + tid * 4);
    const unsigned short* y2v = Y2 + (size_t)t * 20480 + g * 4096 + tid * 16;
    bf16x8 v0 = ((const bf16x8*)y2v)[0];
    bf16x8 v1 = ((const bf16x8*)y2v)[1];
    bf16x4 q0 = *(const bf16x4*)(Y2 + (size_t)t * 20480 + 16384 + g * 1024 + tid * 4);
    bf16x8 kwv = cvt8(kwp + (size_t)g * 2048 + tid * 8);
    float kbv = (tid < 32) ? kbp[g * 32 + tid] : 0.f;

    // ---- stage phase-1 LDS (anchors feats/M/S loads) ----
    {
        bf16x8 v;
        v[0]=(short)f2b(f0.x); v[1]=(short)f2b(f0.y); v[2]=(short)f2b(f0.z); v[3]=(short)f2b(f0.w);
        v[4]=(short)f2b(f1.x); v[5]=(short)f2b(f1.y); v[6]=(short)f2b(f1.z); v[7]=(short)f2b(f1.w);
        *(bf16x8*)(&fB[tid >> 3][(tid & 7) * 8]) = v;
    }
    {   // frag-major decode: element index r = 2*tid (+1), 8-elem runs
        const int r0 = 2 * tid, r1 = 2 * tid + 1;
        int ch = r0 >> 6, lf = r0 & 63;
        *(bf16x8*)(&MtVt[(ch >> 1) * 16 + (lf & 15)][(ch & 1) * 32 + (lf >> 4) * 8]) = m0;
        ch = r1 >> 6; lf = r1 & 63;
        *(bf16x8*)(&MtVt[(ch >> 1) * 16 + (lf & 15)][(ch & 1) * 32 + (lf >> 4) * 8]) = m1;
        // S: 4-elem runs; element index 4*tid
        const int cs = tid >> 7, lsn = (tid >> 1) & 63;
        *(bf16x4*)(&sSQ[cs * 16 + (lsn & 15)][(lsn >> 4) * 8 + (tid & 1) * 4]) = s0;
    }
    if (tid < 32) sKB[tid] = kbv;
    __syncthreads();

    unsigned short* outR = FMS + (size_t)t * 8192 + g * 2048;
    unsigned short* outC = FC  + (size_t)t * 8192 + g * 2048;
    float mean, istd, ls, lq;

    // ================= reg branch =================
    {
        f32x4 accA[2] = {};
        #pragma unroll
        for (int ks = 0; ks < 64; ks += 32) {
            bf16x8 b = *(const bf16x8*)(&MtVt[wave * 16 + l16][ks + quad * 8]);
            #pragma unroll
            for (int mt = 0; mt < 2; ++mt) {
                bf16x8 a = *(const bf16x8*)(&fB[mt * 16 + l16][ks + quad * 8]);
                accA[mt] = __builtin_amdgcn_mfma_f32_16x16x32_bf16(a, b, accA[mt], 0, 0, 0);
            }
        }
        ls = 0.f; lq = 0.f;
        #pragma unroll
        for (int mt = 0; mt < 2; ++mt)
            #pragma unroll
            for (int r = 0; r < 4; ++r) { float v = accA[mt][r]; ls += v; lq += v * v; }
        block_stats2(ls, lq, sRed, tid, 1.0f / 2048.0f, mean, istd);
        #pragma unroll
        for (int mt = 0; mt < 2; ++mt) {
            bf16x4 pk;
            #pragma unroll
            for (int r = 0; r < 4; ++r) {
                float y = (accA[mt][r] - mean) * istd;
                pk[r] = (short)f2b(y > 0.f ? y : 0.f);
            }
            *(bf16x4*)(&XvT[wave * 16 + l16][mt * 16 + quad * 4]) = pk;
        }
        __syncthreads();

        f32x4 accB[2] = {};
        {
            bf16x8 b = *(const bf16x8*)(&XvT[wave * 16 + l16][quad * 8]);
            #pragma unroll
            for (int mt = 0; mt < 2; ++mt) {
                bf16x8 a = *(const bf16x8*)(&sSQ[mt * 16 + l16][quad * 8]);
                accB[mt] = __builtin_amdgcn_mfma_f32_16x16x32_bf16(a, b, accB[mt], 0, 0, 0);
            }
        }
        ls = 0.f; lq = 0.f;
        #pragma unroll
        for (int mt = 0; mt < 2; ++mt)
            #pragma unroll
            for (int r = 0; r < 4; ++r) { float v = accB[mt][r]; ls += v; lq += v * v; }
        block_stats2(ls, lq, sRed, tid, 1.0f / 2048.0f, mean, istd);
        // after this barrier: MtVt and sSQ reads are done
        const int d = wave * 16 + l16;
        #pragma unroll
        for (int mt = 0; mt < 2; ++mt)
            #pragma unroll
            for (int r = 0; r < 4; ++r) {
                float y = (accB[mt][r] - mean) * istd;
                outR[(mt * 16 + quad * 4 + r) * 64 + d] = f2b(y > 0.f ? y : 0.f);
            }
    }

    // ---- stage phase-2 LDS from prefetched regs (no global latency) ----
    {
        const int r0 = 2 * tid, r1 = 2 * tid + 1;
        int ch = r0 >> 6, lf = r0 & 63;
        *(bf16x8*)(&MtVt[(ch >> 1) * 16 + (lf & 15)][(ch & 1) * 32 + (lf >> 4) * 8]) = v0;
        ch = r1 >> 6; lf = r1 & 63;
        *(bf16x8*)(&MtVt[(ch >> 1) * 16 + (lf & 15)][(ch & 1) * 32 + (lf >> 4) * 8]) = v1;
        const int cs = tid >> 7, lsn = (tid >> 1) & 63;
        *(bf16x4*)(&sSQ[cs * 16 + (lsn & 15)][(lsn >> 4) * 8 + (tid & 1) * 4]) = q0;
    }
    __syncthreads();

    // ================= cls branch =================
    {
        f32x4 accA[2] = {};
        #pragma unroll
        for (int ks = 0; ks < 64; ks += 32) {
            bf16x8 b = *(const bf16x8*)(&MtVt[wave * 16 + l16][ks + quad * 8]);
            #pragma unroll
            for (int mt = 0; mt < 2; ++mt) {
                bf16x8 a = *(const bf16x8*)(&fB[mt * 16 + l16][ks + quad * 8]);
                accA[mt] = __builtin_amdgcn_mfma_f32_16x16x32_bf16(a, b, accA[mt], 0, 0, 0);
            }
        }
        ls = 0.f; lq = 0.f;
        #pragma unroll
        for (int mt = 0; mt < 2; ++mt)
            #pragma unroll
            for (int r = 0; r < 4; ++r) { float v = accA[mt][r]; ls += v; lq += v * v; }
        block_stats2(ls, lq, sRed, tid, 1.0f / 2048.0f, mean, istd);
        // after barrier: all fB reads done -> safe to overwrite with kw below
        {
            const int d = wave * 16 + l16;
            #pragma unroll
            for (int mt = 0; mt < 2; ++mt) {
                bf16x4 pk;
                #pragma unroll
                for (int r = 0; r < 4; ++r) {
                    float y = (accA[mt][r] - mean) * istd;
                    unsigned short u = f2b(y > 0.f ? y : 0.f);
                    pk[r] = (short)u;
                    vRM[mt * 16 + quad * 4 + r][d] = (short)u;
                }
                *(bf16x4*)(&XvT[d][mt * 16 + quad * 4]) = pk;   // vT
            }
        }
        // stage kw into fB's space (from prefetched regs)
        *(bf16x8*)(&fB[tid >> 3][(tid & 7) * 8]) = kwv;
        __syncthreads();

        {   // k[i][p] = kw[i]·v[p] + kb
            const int it = wave >> 1, pt = wave & 1;
            f32x4 accK = {};
            #pragma unroll
            for (int ks = 0; ks < 64; ks += 32) {
                bf16x8 a = *(const bf16x8*)(&fB[it * 16 + l16][ks + quad * 8]);
                bf16x8 b = *(const bf16x8*)(&vRM[pt * 16 + l16][ks + quad * 8]);
                accK = __builtin_amdgcn_mfma_f32_16x16x32_bf16(a, b, accK, 0, 0, 0);
            }
            bf16x4 pk;
            #pragma unroll
            for (int r = 0; r < 4; ++r)
                pk[r] = (short)f2b(accK[r] + sKB[it * 16 + quad * 4 + r]);
            *(bf16x4*)(&kT[pt * 16 + l16][it * 16 + quad * 4]) = pk;
        }
        __syncthreads();
        // vRM dead from here; sSC (alias) becomes live

        if (wave < 2) {   // logits + softmax
            f32x4 accL[2] = {};
            bf16x8 a = *(const bf16x8*)(&sSQ[wave * 16 + l16][quad * 8]);
            #pragma unroll
            for (int pt = 0; pt < 2; ++pt) {
                bf16x8 b = *(const bf16x8*)(&kT[pt * 16 + l16][quad * 8]);
                accL[pt] = __builtin_amdgcn_mfma_f32_16x16x32_bf16(a, b, accL[pt], 0, 0, 0);
            }
            #pragma unroll
            for (int r = 0; r < 4; ++r) {
                float a0 = accL[0][r] * 0.125f, a1 = accL[1][r] * 0.125f;
                float mx = fmaxf(a0, a1);
                #pragma unroll
                for (int m = 1; m < 16; m <<= 1) mx = fmaxf(mx, __shfl_xor(mx, m, 64));
                a0 = __expf(a0 - mx); a1 = __expf(a1 - mx);
                float sum = a0 + a1;
                #pragma unroll
                for (int m = 1; m < 16; m <<= 1) sum += __shfl_xor(sum, m, 64);
                const float inv_s = 1.0f / sum;
                const int o = wave * 16 + quad * 4 + r;
                sSC[o][l16]      = (short)f2b(a0 * inv_s);
                sSC[o][16 + l16] = (short)f2b(a1 * inv_s);
            }
        }
        __syncthreads();

        f32x4 accB[2] = {};
        {
            bf16x8 b = *(const bf16x8*)(&XvT[wave * 16 + l16][quad * 8]);
            #pragma unroll
            for (int mt = 0; mt < 2; ++mt) {
                bf16x8 a = *(const bf16x8*)(&sSC[mt * 16 + l16][quad * 8]);
                accB[mt] = __builtin_amdgcn_mfma_f32_16x16x32_bf16(a, b, accB[mt], 0, 0, 0);
            }
        }
        ls = 0.f; lq = 0.f;
        #pragma unroll
        for (int mt = 0; mt < 2; ++mt)
            #pragma unroll
            for (int r = 0; r < 4; ++r) { float v = accB[mt][r]; ls += v; lq += v * v; }
        block_stats2(ls, lq, sRed, tid, 1.0f / 2048.0f, mean, istd);

        const int d = wave * 16 + l16;
        #pragma unroll
        for (int mt = 0; mt < 2; ++mt)
            #pragma unroll
            for (int r = 0; r < 4; ++r) {
                float y = (accB[mt][r] - mean) * istd;
                outC[(mt * 16 + quad * 4 + r) * 64 + d] = f2b(y > 0.f ? y : 0.f);
            }
    }
}

// ---------------------------------------------------------------------------
// Final: reduce split-K=8 partials, residual add, affine LN over 256, fp32 out.
// ---------------------------------------------------------------------------
__global__ __launch_bounds__(256) void final_ln_kernel(
    const float* __restrict__ qv,
    const float* __restrict__ MSP, const float* __restrict__ CLP,
    const float* __restrict__ Wv_b, const float* __restrict__ Wv2_b,
    const float* __restrict__ lnA_w, const float* __restrict__ lnA_b,
    const float* __restrict__ lnB_w, const float* __restrict__ lnB_b,
    float* __restrict__ out)
{
    __shared__ float sRed[16];
    const int t = blockIdx.x;
    const int br = blockIdx.y;
    const int c = threadIdx.x;
    const float* P = br ? CLP : MSP;
    const float* bias = br ? Wv2_b : Wv_b;
    const float* lw = br ? lnB_w : lnA_w;
    const float* lb = br ? lnB_b : lnA_b;

    float x = qv[t * 256 + c] + bias[c];
    #pragma unroll
    for (int s = 0; s < 8; ++s) x += P[(size_t)s * (BN * 256) + t * 256 + c];

    float mean, istd;
    block_stats(x, x * x, sRed, c, 1.0f / 256.0f, mean, istd);
    out[(size_t)br * (BN * 256) + t * 256 + c] = (x - mean) * istd * lw[c] + lb[c];
}

// ---------------------------------------------------------------------------
extern "C" void kernel_launch(void* const* d_in, const int* in_sizes, int n_in,
                              void* d_out, int out_size, void* d_ws, size_t ws_size,
                              hipStream_t stream) {
    const float* feats = (const float*)d_in[0];
    const float* qv    = (const float*)d_in[1];
    const float* m_w   = (const float*)d_in[7];
    const float* m_b   = (const float*)d_in[8];
    const float* s_w   = (const float*)d_in[9];
    const float* s_b   = (const float*)d_in[10];
    const float* q_w   = (const float*)d_in[11];
    const float* q_b   = (const float*)d_in[12];
    const float* v_w   = (const float*)d_in[13];
    const float* v_b   = (const float*)d_in[14];
    const float* k_w   = (const float*)d_in[15];
    const float* k_b   = (const float*)d_in[16];
    const float* Wv_w  = (const float*)d_in[17];
    const float* Wv_b  = (const float*)d_in[18];
    const float* Wv2_w = (const float*)d_in[19];
    const float* Wv2_b = (const float*)d_in[20];
    const float* lnA_w = (const float*)d_in[21];
    const float* lnA_b = (const float*)d_in[22];
    const float* lnB_w = (const float*)d_in[23];
    const float* lnB_b = (const float*)d_in[24];

    char* ws = (char*)d_ws;
    const dim3 blk(256);

    if (ws_size >= 275251200ull) {
        // ===== BIG path (275.3 MB) =====
        unsigned short* Y1 = (unsigned short*)(ws);
        unsigned short* Y2 = (unsigned short*)(ws + 98304000);
        unsigned short* W1   = (unsigned short*)(ws + 196608000);
        unsigned short* W2   = (unsigned short*)(ws + 196608000 + 10485760);
        unsigned short* qvP  = (unsigned short*)(ws + 196608000 + 20971520);
        float* b1 = (float*)(ws + 196608000 + 22216704);
        float* b2 = (float*)(ws + 196608000 + 22298624);
        unsigned short* FMS = (unsigned short*)(ws + 196608000);
        unsigned short* FC  = (unsigned short*)(ws + 235929600);
        unsigned short* WvB  = (unsigned short*)(ws + 98304000);
        unsigned short* Wv2B = (unsigned short*)(ws + 98304000 + 4194304);
        float* MSP = (float*)(ws);
        float* CLP = (float*)(ws + 19660800);

        prep_perm_kernel<<<dim3(4096, 2), blk, 0, stream>>>(m_w, m_b, W1, b1,
                                                            v_w, v_b, W2, b2);
        prep_flat_frag_kernel<<<dim3(512, 2), blk, 0, stream>>>(s_w, W1, q_w, W2);
        prep_pack_a_kernel<<<304, blk, 0, stream>>>(qv, qvP);
        copy_bias_kernel<<<dim3(16, 2), blk, 0, stream>>>(s_b, b1 + 16384, q_b, b2 + 16384);
        gemm_gen_kernel<<<dim3(19, 320), blk, 0, stream>>>(
            qvP, W1, b1, Y1, W2, b2, Y2, 160, BN, 20480);
        p2_fused_kernel<<<dim3(BN, NG), blk, 0, stream>>>(
            feats, Y1, Y2, k_w, k_b, FMS, FC);
        prep_flat_kernel<<<dim3(1024, 2), blk, 0, stream>>>(
            Wv_w, WvB, 256 * 8192, Wv2_w, Wv2B, 256 * 8192, nullptr, nullptr, 0);
        gemm_proj_kernel<<<dim3(38, 4, 16), blk, 0, stream>>>(
            FMS, WvB, MSP, FC, Wv2B, CLP, 8, BN, 256, 8192, 1024);
        final_ln_kernel<<<dim3(BN, 2), blk, 0, stream>>>(
            qv, MSP, CLP, Wv_b, Wv2_b, lnA_w, lnA_b, lnB_w, lnB_b, (float*)d_out);
    } else {
        // ===== SMALL path (176.9 MB fallback) =====
        unsigned short* Y1  = (unsigned short*)(ws);
        unsigned short* FMS = (unsigned short*)(ws + 98304000);
        unsigned short* FC  = (unsigned short*)(ws + 137625600);
        unsigned short* W1   = (unsigned short*)(ws + 137625600);
        unsigned short* W2   = (unsigned short*)(ws + 137625600 + 10485760);
        unsigned short* qvP  = (unsigned short*)(ws + 137625600 + 20971520);
        float* b1 = (float*)(ws + 137625600 + 22216704);
        float* b2 = (float*)(ws + 137625600 + 22298624);
        float* MSP = (float*)(ws);
        float* CLP = (float*)(ws + 19660800);
        unsigned short* WvB  = (unsigned short*)(ws + 39321600);
        unsigned short* Wv2B = (unsigned short*)(ws + 43515904);

        prep_perm_kernel<<<dim3(4096, 2), blk, 0, stream>>>(m_w, m_b, W1, b1,
                                                            v_w, v_b, W2, b2);
        prep_flat_frag_kernel<<<dim3(512, 2), blk, 0, stream>>>(s_w, W1, q_w, W2);
        prep_pack_a_kernel<<<304, blk, 0, stream>>>(qv, qvP);
        copy_bias_kernel<<<dim3(16, 2), blk, 0, stream>>>(s_b, b1 + 16384, q_b, b2 + 16384);
        gemm_gen_kernel<<<dim3(19, 160), blk, 0, stream>>>(
            qvP, W1, b1, Y1, W1, b1, Y1, 160, BN, 20480);
        p2_reg_kernel<<<dim3(BN, NG), blk, 0, stream>>>(feats, Y1, FMS);
        gemm_gen_kernel<<<dim3(19, 160), blk, 0, stream>>>(
            qvP, W2, b2, Y1, W2, b2, Y1, 160, BN, 20480);
        p2_cls_kernel<<<dim3(BN, NG), blk, 0, stream>>>(feats, Y1, k_w, k_b, FC);
        prep_flat_kernel<<<dim3(1024, 2), blk, 0, stream>>>(
            Wv_w, WvB, 256 * 8192, Wv2_w, Wv2B, 256 * 8192, nullptr, nullptr, 0);
        gemm_proj_kernel<<<dim3(38, 4, 8), blk, 0, stream>>>(
            FMS, WvB, MSP, FMS, WvB, MSP, 8, BN, 256, 8192, 1024);
        gemm_proj_kernel<<<dim3(38, 4, 8), blk, 0, stream>>>(
            FC, Wv2B, CLP, FC, Wv2B, CLP, 8, BN, 256, 8192, 1024);
        final_ln_kernel<<<dim3(BN, 2), blk, 0, stream>>>(
            qv, MSP, CLP, Wv_b, Wv2_b, lnA_w, lnA_b, lnB_w, lnB_b, (float*)d_out);
    }
}

// Round 10
// 392.983 us; speedup vs baseline: 1.0961x; 1.0290x over previous
//
#include <hip/hip_runtime.h>

// Problem constants
#define BN    2400   // B*N
#define NG    4      // groups
#define DIM   256

// R21: proj GEMM full-N rework (p2_fused kept at R20's proven 82us).
//  - gemm_proj: 64x256 tile (full N) so the streamed A (FMS/FC, 78MB) is
//    read from HBM exactly ONCE (was 4x with 64x64 tiles). B (8MB, L2-hot)
//    is pre-packed FRAGMENT-MAJOR by prep_projw -> B-frag loads are single
//    coalesced 1KB wave transactions (the R12/R13-proven regime: packed +
//    cache-hot; avoids the R15 gather failure). A stays LDS-staged (9.2KB).
//    Grid 38x16, 4 waves x 64x64 n-quarter, 32 MFMA/wave per K-64 step.
//  - prep_flat replaced by prep_projw_kernel (same buffers/offsets).
// All other kernels byte-identical to R20.

typedef __attribute__((ext_vector_type(8))) short bf16x8;
typedef __attribute__((ext_vector_type(4))) short bf16x4;
typedef __attribute__((ext_vector_type(4))) float f32x4;

__device__ __forceinline__ float b2f(unsigned short u) {
    union { unsigned int i; float f; } v; v.i = ((unsigned int)u) << 16; return v.f;
}
__device__ __forceinline__ unsigned short f2b(float f) {
    union { float f; unsigned int i; } v; v.f = f;
    unsigned int x = v.i;
    return (unsigned short)((x + 0x7fffu + ((x >> 16) & 1u)) >> 16);  // RNE
}

__device__ __forceinline__ void glds16(const unsigned short* g, const short* l) {
    __builtin_amdgcn_global_load_lds(
        (const __attribute__((address_space(1))) unsigned int*)(const void*)g,
        (__attribute__((address_space(3))) unsigned int*)(void*)const_cast<short*>(l),
        16, 0, 0);
}

__device__ __forceinline__ bf16x8 cvt8(const float* p) {
    float4 x0 = ((const float4*)p)[0];
    float4 x1 = ((const float4*)p)[1];
    bf16x8 v;
    v[0]=(short)f2b(x0.x); v[1]=(short)f2b(x0.y); v[2]=(short)f2b(x0.z); v[3]=(short)f2b(x0.w);
    v[4]=(short)f2b(x1.x); v[5]=(short)f2b(x1.y); v[6]=(short)f2b(x1.z); v[7]=(short)f2b(x1.w);
    return v;
}

__device__ __forceinline__ void block_stats(float s, float q, float* sRed, int tid,
                                            float inv_n, float& mean, float& istd) {
    #pragma unroll
    for (int off = 32; off > 0; off >>= 1) {
        s += __shfl_down(s, off, 64);
        q += __shfl_down(q, off, 64);
    }
    if ((tid & 63) == 0) { sRed[(tid >> 6) * 2] = s; sRed[(tid >> 6) * 2 + 1] = q; }
    __syncthreads();
    if (tid == 0) {
        float ts = 0.f, tq = 0.f;
        for (int w = 0; w < 4; ++w) { ts += sRed[2 * w]; tq += sRed[2 * w + 1]; }
        float m = ts * inv_n;
        float var = tq * inv_n - m * m;
        sRed[8] = m; sRed[9] = rsqrtf(var + 1e-5f);
    }
    __syncthreads();
    mean = sRed[8]; istd = sRed[9];
}

// single-barrier variant: leaders write partials; every thread reduces the
// 4 partial pairs itself. Caller guarantees a __syncthreads between
// consecutive calls (true in p2_fused_kernel).
__device__ __forceinline__ void block_stats2(float s, float q, float* sRed, int tid,
                                             float inv_n, float& mean, float& istd) {
    #pragma unroll
    for (int off = 32; off > 0; off >>= 1) {
        s += __shfl_down(s, off, 64);
        q += __shfl_down(q, off, 64);
    }
    if ((tid & 63) == 0) { sRed[(tid >> 6) * 2] = s; sRed[(tid >> 6) * 2 + 1] = q; }
    __syncthreads();
    float ts = 0.f, tq = 0.f;
    #pragma unroll
    for (int w = 0; w < 4; ++w) { ts += sRed[2 * w]; tq += sRed[2 * w + 1]; }
    mean = ts * inv_n;
    float var = tq * inv_n - mean * mean;
    istd = rsqrtf(var + 1e-5f);
}

// ---------------------------------------------------------------------------
// Weight preps. Output-column order n is FRAG-MAJOR (unchanged from R17).
// ---------------------------------------------------------------------------
__global__ __launch_bounds__(256) void prep_perm_kernel(
    const float* __restrict__ wA, const float* __restrict__ bA,
    unsigned short* __restrict__ oA, float* __restrict__ obA,
    const float* __restrict__ wB, const float* __restrict__ bB,
    unsigned short* __restrict__ oB, float* __restrict__ obB)
{
    const float* w = blockIdx.y ? wB : wA;
    const float* b = blockIdx.y ? bB : bA;
    unsigned short* wOut = blockIdx.y ? oB : oA;
    float* bOut = blockIdx.y ? obB : obA;

    const int n = blockIdx.x * 4 + (threadIdx.x >> 6);   // frag-major output col
    const int lane = threadIdx.x & 63;
    // decode (g,d,c) from frag-major n
    const int g = n >> 12, qq = n & 4095;
    const int chunk = qq >> 9, lf = (qq >> 3) & 63, jj = qq & 7;
    const int d = (chunk >> 1) * 16 + (lf & 15);
    const int c = (chunk & 1) * 32 + (lf >> 4) * 8 + jj;
    const int row_i = (g << 12) + c * 64 + d;            // source weight row

    const float4 x = *(const float4*)(w + (size_t)row_i * 256 + lane * 4);
    bf16x4 pk;
    pk[0] = (short)f2b(x.x); pk[1] = (short)f2b(x.y);
    pk[2] = (short)f2b(x.z); pk[3] = (short)f2b(x.w);

    const int k0 = lane * 4;
    const int nt = n >> 6, rg = (n >> 4) & 3, r16 = n & 15;
    const int kc = k0 >> 5, q = (k0 >> 3) & 3, j = k0 & 7;
    const int lp = r16 | (q << 4);
    *(bf16x4*)(wOut + ((((size_t)(nt * 8 + kc) * 4 + rg) * 64 + lp) * 8 + j)) = pk;
    if (lane == 0) bOut[n] = b[row_i];
}

__global__ __launch_bounds__(256) void prep_flat_frag_kernel(
    const float* __restrict__ a0, unsigned short* __restrict__ o0,
    const float* __restrict__ a1, unsigned short* __restrict__ o1)
{
    const float* src = blockIdx.y ? a1 : a0;
    unsigned short* dst = blockIdx.y ? o1 : o0;
    const int idx = (blockIdx.x * 256 + threadIdx.x) * 8;
    if (idx >= 4096 * 256) return;
    bf16x8 v = cvt8(src + idx);

    const int r = idx >> 8;
    const int k0 = idx & 255;
    const int g = r >> 10, o = (r >> 5) & 31, i = r & 31;
    const int n = 16384 + g * 1024 + (o >> 4) * 512
                + ((o & 15) + 16 * ((i >> 3) & 3)) * 8 + (i & 7);
    const int nt = n >> 6, rg = (n >> 4) & 3, r16 = n & 15;
    const int kc = k0 >> 5, q = (k0 >> 3) & 3;
    const int lp = r16 | (q << 4);
    *(bf16x8*)(dst + (((size_t)(nt * 8 + kc) * 4 + rg) * 64 + lp) * 8) = v;
}

// frag-major pack of projection weights Wv/Wv2 ([256][8192] fp32 row-major):
// elem(n,k) = (((nt*256 + kc)*4 + rg)*64 + (r16|(q<<4)))*8 + j
// with nt=n>>6, rg=(n>>4)&3, r16=n&15, kc=k>>5, q=(k>>3)&3, j=k&7.
__global__ __launch_bounds__(256) void prep_projw_kernel(
    const float* __restrict__ a0, unsigned short* __restrict__ o0,
    const float* __restrict__ a1, unsigned short* __restrict__ o1)
{
    const float* src = blockIdx.y ? a1 : a0;
    unsigned short* dst = blockIdx.y ? o1 : o0;
    const int chunk = blockIdx.x * 256 + threadIdx.x;   // 0 .. 262143
    const int n = chunk >> 10;
    const int k0 = (chunk & 1023) * 8;
    bf16x8 v = cvt8(src + (size_t)n * 8192 + k0);

    const int nt = n >> 6, rg = (n >> 4) & 3, r16 = n & 15;
    const int kc = k0 >> 5, q = (k0 >> 3) & 3;
    const int lp = r16 | (q << 4);
    *(bf16x8*)(dst + (((size_t)(nt * 256 + kc) * 4 + rg) * 64 + lp) * 8) = v;
}

// permuted S/Q bias copy: dst[pS(r)] = src[r]
__global__ __launch_bounds__(256) void copy_bias_kernel(
    const float* __restrict__ a0, float* __restrict__ o0,
    const float* __restrict__ a1, float* __restrict__ o1)
{
    const int r = blockIdx.x * 256 + threadIdx.x;
    const int g = r >> 10, o = (r >> 5) & 31, i = r & 31;
    const int p = g * 1024 + (o >> 4) * 512
                + ((o & 15) + 16 * ((i >> 3) & 3)) * 8 + (i & 7);
    if (blockIdx.y == 0) o0[p] = a0[r]; else o1[p] = a1[r];
}

__global__ __launch_bounds__(256) void prep_pack_a_kernel(
    const float* __restrict__ qv, unsigned short* __restrict__ qvP)
{
    const int idx = blockIdx.x * 256 + threadIdx.x;   // chunk index
    if (idx >= 38 * 8 * 4 * 64) return;
    const int lane = idx & 63;
    const int rg   = (idx >> 6) & 3;
    const int kc   = (idx >> 8) & 7;
    const int mt   = idx >> 11;
    int row = mt * 64 + rg * 16 + (lane & 15);
    if (row >= BN) row = BN - 1;
    const int col = kc * 32 + (lane >> 4) * 8;
    *(bf16x8*)(qvP + (size_t)idx * 8) = cvt8(qv + (size_t)row * 256 + col);
}

// ---------------------------------------------------------------------------
// Generator GEMM (unchanged).
// ---------------------------------------------------------------------------
__global__ __launch_bounds__(256) void gemm_gen_kernel(
    const unsigned short* __restrict__ qvP,
    const unsigned short* __restrict__ W1, const float* __restrict__ b1,
    unsigned short* __restrict__ C1,
    const unsigned short* __restrict__ W2, const float* __restrict__ b2,
    unsigned short* __restrict__ C2,
    int ySplit, int M, int N)
{
    __shared__ __align__(16) char smem[33792];
    short (*sB)[16][64][8] = (short (*)[16][64][8])smem;
    short (*sC)[132]       = (short (*)[132])smem;

    const int flat = blockIdx.y * gridDim.x + blockIdx.x;
    const int nwg = gridDim.x * gridDim.y;
    const int wg = (flat & 7) * (nwg >> 3) + (flat >> 3);
    const int mb = wg % gridDim.x;
    const int nb = wg / gridDim.x;

    const bool s2 = (nb >= ySplit);
    const unsigned short* Wp = s2 ? W2 : W1;
    const float* bias = s2 ? b2 : b1;
    unsigned short* C = s2 ? C2 : C1;
    const int nbb = s2 ? nb - ySplit : nb;

    const int tid = threadIdx.x;
    const int lane = tid & 63;
    const int wave = tid >> 6;
    const int l16 = lane & 15;
    const int quad = lane >> 4;
    const int wmi = wave >> 1;
    const int wni = wave & 1;

    const int ntl = wave >> 1, kcl = wave & 1;
    const unsigned short* bSrc = Wp + (size_t)(nbb * 2 + ntl) * 16384;
    const unsigned short* aW = qvP + (size_t)(mb * 2 + wmi) * 16384;

    f32x4 acc[4][4] = {};

    #pragma unroll
    for (int r = 0; r < 4; ++r)
        glds16(bSrc + ((size_t)(0 + kcl) * 4 + r) * 512 + lane * 8,
               &sB[0][(ntl * 2 + kcl) * 4 + r][0][0]);
    __syncthreads();

    int buf = 0;
    for (int t = 0; t < 4; ++t) {
        if (t < 3) {
            #pragma unroll
            for (int r = 0; r < 4; ++r)
                glds16(bSrc + ((size_t)(2 * (t + 1) + kcl) * 4 + r) * 512 + lane * 8,
                       &sB[buf ^ 1][(ntl * 2 + kcl) * 4 + r][0][0]);
        }
        bf16x8 af[2][4];
        #pragma unroll
        for (int kci = 0; kci < 2; ++kci)
            #pragma unroll
            for (int m = 0; m < 4; ++m)
                af[kci][m] = *(const bf16x8*)(aW + ((size_t)(2 * t + kci) * 4 + m) * 512 + lane * 8);
        #pragma unroll
        for (int kci = 0; kci < 2; ++kci) {
            bf16x8 bfv[4];
            #pragma unroll
            for (int n = 0; n < 4; ++n)
                bfv[n] = *(const bf16x8*)(&sB[buf][(wni * 2 + kci) * 4 + n][lane][0]);
            #pragma unroll
            for (int m = 0; m < 4; ++m)
                #pragma unroll
                for (int n = 0; n < 4; ++n)
                    acc[m][n] = __builtin_amdgcn_mfma_f32_16x16x32_bf16(
                        af[kci][m], bfv[n], acc[m][n], 0, 0, 0);
        }
        __syncthreads();
        buf ^= 1;
    }

    #pragma unroll
    for (int n = 0; n < 4; ++n) {
        const int col = wni * 64 + n * 16 + l16;
        const float bv = bias[nbb * 128 + col];
        #pragma unroll
        for (int m = 0; m < 4; ++m) {
            const int row = wmi * 64 + m * 16 + quad * 4;
            #pragma unroll
            for (int r = 0; r < 4; ++r)
                sC[row + r][col] = (short)f2b(acc[m][n][r] + bv);
        }
    }
    __syncthreads();

    {
        const int m0 = mb * 128, n0 = nbb * 128;
        #pragma unroll
        for (int i = 0; i < 8; ++i) {
            const int row = wave * 32 + i * 4 + quad;
            const int grow = m0 + row;
            if (grow < M) {
                bf16x4 lo = *(const bf16x4*)(&sC[row][l16 * 8]);
                bf16x4 hi = *(const bf16x4*)(&sC[row][l16 * 8 + 4]);
                bf16x8 v;
                v[0]=lo[0]; v[1]=lo[1]; v[2]=lo[2]; v[3]=lo[3];
                v[4]=hi[0]; v[5]=hi[1]; v[6]=hi[2]; v[7]=hi[3];
                *(bf16x8*)(C + (size_t)grow * N + n0 + l16 * 8) = v;
            }
        }
    }
}

// ---------------------------------------------------------------------------
// Projection GEMM — R21 full-N: 64x256 tile, A LDS-staged (read once from
// HBM), B direct from frag-major packed WvB/Wv2B (coalesced, L2-hot).
// Grid (38, zTotal): blockIdx.y selects branch/K-slice.
// ---------------------------------------------------------------------------
__global__ __launch_bounds__(256) void gemm_proj_kernel(
    const unsigned short* __restrict__ A1, const unsigned short* __restrict__ W1,
    float* __restrict__ C1,
    const unsigned short* __restrict__ A2, const unsigned short* __restrict__ W2,
    float* __restrict__ C2,
    int zSplit, int M, int N, int ldK, int kLen)
{
    __shared__ short sA[64][72];

    const int z = blockIdx.y;
    const bool s2 = (z >= zSplit);
    const int zi = s2 ? z - zSplit : z;
    const unsigned short* A = s2 ? A2 : A1;
    const unsigned short* Wp = s2 ? W2 : W1;
    float* C = (s2 ? C2 : C1) + (size_t)zi * M * N;

    const int m0 = blockIdx.x * 64;
    const int tid = threadIdx.x;
    const int lane = tid & 63;
    const int wave = tid >> 6;          // n-quarter (0..3)
    const int l16 = lane & 15;
    const int quad = lane >> 4;
    const int lr = tid >> 2;
    const int lc = (tid & 3) * 16;

    const int kcStride = ldK >> 5;      // K-chunks per row (256)
    const int kbase = zi * kLen;

    f32x4 acc[4][4] = {};               // [m-frag][n-frag]

    for (int kt = 0; kt < kLen; kt += 64) {
        {   // stage A 64x64 (coalesced 2x16B per thread)
            const int gr = m0 + lr;
            bf16x8 a0 = {}, a1 = {};
            if (gr < M) {
                const unsigned short* ap = A + (size_t)gr * ldK + kbase + kt + lc;
                a0 = ((const bf16x8*)ap)[0];
                a1 = ((const bf16x8*)ap)[1];
            }
            *(bf16x8*)(&sA[lr][lc])     = a0;
            *(bf16x8*)(&sA[lr][lc + 8]) = a1;
        }
        __syncthreads();
        #pragma unroll
        for (int kci = 0; kci < 2; ++kci) {
            const int kc = ((kbase + kt) >> 5) + kci;
            bf16x8 bfv[4];
            #pragma unroll
            for (int nf = 0; nf < 4; ++nf)
                bfv[nf] = *(const bf16x8*)(Wp +
                    (((size_t)(wave * kcStride + kc) * 4 + nf) * 64 + lane) * 8);
            bf16x8 av[4];
            #pragma unroll
            for (int mf = 0; mf < 4; ++mf)
                av[mf] = *(const bf16x8*)(&sA[mf * 16 + l16][kci * 32 + quad * 8]);
            #pragma unroll
            for (int mf = 0; mf < 4; ++mf)
                #pragma unroll
                for (int nf = 0; nf < 4; ++nf)
                    acc[mf][nf] = __builtin_amdgcn_mfma_f32_16x16x32_bf16(
                        av[mf], bfv[nf], acc[mf][nf], 0, 0, 0);
        }
        __syncthreads();
    }

    #pragma unroll
    for (int mf = 0; mf < 4; ++mf)
        #pragma unroll
        for (int nf = 0; nf < 4; ++nf) {
            const int col = wave * 64 + nf * 16 + l16;
            #pragma unroll
            for (int r = 0; r < 4; ++r) {
                const int row = m0 + mf * 16 + quad * 4 + r;
                if (row < M)
                    C[(size_t)row * N + col] = acc[mf][nf][r];
            }
        }
}

// ===========================================================================
// Phase-2 device helpers (small-ws split kernels; frag-aware, unchanged).
// ===========================================================================
__device__ __forceinline__ void p2_stage_feats(
    const float* fp, short (*fB)[72], int tid)
{
    *(bf16x8*)(&fB[tid >> 3][(tid & 7) * 8]) = cvt8(fp + tid * 8);
}

// frag-major 64x64 tile -> LDS [d][c]
__device__ __forceinline__ void p2_stage_64x64(
    const unsigned short* mp, short (*T)[72], int tid)
{
    #pragma unroll
    for (int h = 0; h < 2; ++h) {
        const int ri = tid + h * 256;               // 0..511 runs of 8
        bf16x8 v = *(const bf16x8*)(mp + ri * 8);
        const int chunk = ri >> 6, lf = ri & 63;
        const int d = (chunk >> 1) * 16 + (lf & 15);
        const int c = (chunk & 1) * 32 + (lf >> 4) * 8;
        *(bf16x8*)(&T[d][c]) = v;
    }
}

// frag-major 32x32 tile -> LDS [o][i]
__device__ __forceinline__ void p2_stage_32x32(
    const unsigned short* sp, short (*T)[40], int tid)
{
    if (tid < 128) {
        bf16x8 v = *(const bf16x8*)(sp + tid * 8);
        const int chunk = tid >> 6, lf = tid & 63;
        const int o = chunk * 16 + (lf & 15);
        const int i = (lf >> 4) * 8;
        *(bf16x8*)(&T[o][i]) = v;
    }
}

__device__ __forceinline__ void p2_reg_body(
    short (*fB)[72], short (*Mt)[72], short (*sS)[40], short (*X1T)[40],
    float* sRed, unsigned short* outp, int tid)
{
    const int wave = tid >> 6, lane = tid & 63;
    const int l16 = lane & 15, quad = lane >> 4;

    f32x4 accA[2] = {};
    #pragma unroll
    for (int ks = 0; ks < 64; ks += 32) {
        bf16x8 b = *(const bf16x8*)(&Mt[wave * 16 + l16][ks + quad * 8]);
        #pragma unroll
        for (int mt = 0; mt < 2; ++mt) {
            bf16x8 a = *(const bf16x8*)(&fB[mt * 16 + l16][ks + quad * 8]);
            accA[mt] = __builtin_amdgcn_mfma_f32_16x16x32_bf16(a, b, accA[mt], 0, 0, 0);
        }
    }
    float ls = 0.f, lq = 0.f;
    #pragma unroll
    for (int mt = 0; mt < 2; ++mt)
        #pragma unroll
        for (int r = 0; r < 4; ++r) { float v = accA[mt][r]; ls += v; lq += v * v; }
    float mean, istd;
    block_stats(ls, lq, sRed, tid, 1.0f / 2048.0f, mean, istd);
    #pragma unroll
    for (int mt = 0; mt < 2; ++mt) {
        bf16x4 pk;
        #pragma unroll
        for (int r = 0; r < 4; ++r) {
            float y = (accA[mt][r] - mean) * istd;
            pk[r] = (short)f2b(y > 0.f ? y : 0.f);
        }
        *(bf16x4*)(&X1T[wave * 16 + l16][mt * 16 + quad * 4]) = pk;
    }
    __syncthreads();

    f32x4 accB[2] = {};
    {
        bf16x8 b = *(const bf16x8*)(&X1T[wave * 16 + l16][quad * 8]);
        #pragma unroll
        for (int mt = 0; mt < 2; ++mt) {
            bf16x8 a = *(const bf16x8*)(&sS[mt * 16 + l16][quad * 8]);
            accB[mt] = __builtin_amdgcn_mfma_f32_16x16x32_bf16(a, b, accB[mt], 0, 0, 0);
        }
    }
    ls = 0.f; lq = 0.f;
    #pragma unroll
    for (int mt = 0; mt < 2; ++mt)
        #pragma unroll
        for (int r = 0; r < 4; ++r) { float v = accB[mt][r]; ls += v; lq += v * v; }
    block_stats(ls, lq, sRed, tid, 1.0f / 2048.0f, mean, istd);

    const int d = wave * 16 + l16;
    #pragma unroll
    for (int mt = 0; mt < 2; ++mt)
        #pragma unroll
        for (int r = 0; r < 4; ++r) {
            float y = (accB[mt][r] - mean) * istd;
            outp[(mt * 16 + quad * 4 + r) * 64 + d] = f2b(y > 0.f ? y : 0.f);
        }
}

__device__ __forceinline__ void p2_cls_body(
    short (*fB)[72], short (*Vt)[72], short (*kw)[72], short (*vRM)[72],
    short (*vT)[40], short (*kT)[40], short (*sQ)[40], short (*sSC)[40],
    float* sKB, float* sRed, unsigned short* outp, int tid)
{
    const int wave = tid >> 6, lane = tid & 63;
    const int l16 = lane & 15, quad = lane >> 4;

    f32x4 accA[2] = {};
    #pragma unroll
    for (int ks = 0; ks < 64; ks += 32) {
        bf16x8 b = *(const bf16x8*)(&Vt[wave * 16 + l16][ks + quad * 8]);
        #pragma unroll
        for (int mt = 0; mt < 2; ++mt) {
            bf16x8 a = *(const bf16x8*)(&fB[mt * 16 + l16][ks + quad * 8]);
            accA[mt] = __builtin_amdgcn_mfma_f32_16x16x32_bf16(a, b, accA[mt], 0, 0, 0);
        }
    }
    float ls = 0.f, lq = 0.f;
    #pragma unroll
    for (int mt = 0; mt < 2; ++mt)
        #pragma unroll
        for (int r = 0; r < 4; ++r) { float v = accA[mt][r]; ls += v; lq += v * v; }
    float mean, istd;
    block_stats(ls, lq, sRed, tid, 1.0f / 2048.0f, mean, istd);
    {
        const int d = wave * 16 + l16;
        #pragma unroll
        for (int mt = 0; mt < 2; ++mt) {
            bf16x4 pk;
            #pragma unroll
            for (int r = 0; r < 4; ++r) {
                float y = (accA[mt][r] - mean) * istd;
                unsigned short u = f2b(y > 0.f ? y : 0.f);
                pk[r] = (short)u;
                vRM[mt * 16 + quad * 4 + r][d] = (short)u;
            }
            *(bf16x4*)(&vT[d][mt * 16 + quad * 4]) = pk;
        }
    }
    __syncthreads();

    {
        const int it = wave >> 1, pt = wave & 1;
        f32x4 accK = {};
        #pragma unroll
        for (int ks = 0; ks < 64; ks += 32) {
            bf16x8 a = *(const bf16x8*)(&kw[it * 16 + l16][ks + quad * 8]);
            bf16x8 b = *(const bf16x8*)(&vRM[pt * 16 + l16][ks + quad * 8]);
            accK = __builtin_amdgcn_mfma_f32_16x16x32_bf16(a, b, accK, 0, 0, 0);
        }
        bf16x4 pk;
        #pragma unroll
        for (int r = 0; r < 4; ++r)
            pk[r] = (short)f2b(accK[r] + sKB[it * 16 + quad * 4 + r]);
        *(bf16x4*)(&kT[pt * 16 + l16][it * 16 + quad * 4]) = pk;
    }
    __syncthreads();

    if (wave < 2) {
        f32x4 accL[2] = {};
        bf16x8 a = *(const bf16x8*)(&sQ[wave * 16 + l16][quad * 8]);
        #pragma unroll
        for (int pt = 0; pt < 2; ++pt) {
            bf16x8 b = *(const bf16x8*)(&kT[pt * 16 + l16][quad * 8]);
            accL[pt] = __builtin_amdgcn_mfma_f32_16x16x32_bf16(a, b, accL[pt], 0, 0, 0);
        }
        #pragma unroll
        for (int r = 0; r < 4; ++r) {
            float a0 = accL[0][r] * 0.125f, a1 = accL[1][r] * 0.125f;
            float mx = fmaxf(a0, a1);
            #pragma unroll
            for (int m = 1; m < 16; m <<= 1) mx = fmaxf(mx, __shfl_xor(mx, m, 64));
            a0 = __expf(a0 - mx); a1 = __expf(a1 - mx);
            float sum = a0 + a1;
            #pragma unroll
            for (int m = 1; m < 16; m <<= 1) sum += __shfl_xor(sum, m, 64);
            const float inv_s = 1.0f / sum;
            const int o = wave * 16 + quad * 4 + r;
            sSC[o][l16]      = (short)f2b(a0 * inv_s);
            sSC[o][16 + l16] = (short)f2b(a1 * inv_s);
        }
    }
    __syncthreads();

    f32x4 accB[2] = {};
    {
        bf16x8 b = *(const bf16x8*)(&vT[wave * 16 + l16][quad * 8]);
        #pragma unroll
        for (int mt = 0; mt < 2; ++mt) {
            bf16x8 a = *(const bf16x8*)(&sSC[mt * 16 + l16][quad * 8]);
            accB[mt] = __builtin_amdgcn_mfma_f32_16x16x32_bf16(a, b, accB[mt], 0, 0, 0);
        }
    }
    ls = 0.f; lq = 0.f;
    #pragma unroll
    for (int mt = 0; mt < 2; ++mt)
        #pragma unroll
        for (int r = 0; r < 4; ++r) { float v = accB[mt][r]; ls += v; lq += v * v; }
    block_stats(ls, lq, sRed, tid, 1.0f / 2048.0f, mean, istd);

    const int d = wave * 16 + l16;
    #pragma unroll
    for (int mt = 0; mt < 2; ++mt)
        #pragma unroll
        for (int r = 0; r < 4; ++r) {
            float y = (accB[mt][r] - mean) * istd;
            outp[(mt * 16 + quad * 4 + r) * 64 + d] = f2b(y > 0.f ? y : 0.f);
        }
}

__device__ __forceinline__ void p2_stage_cls(
    const unsigned short* Y2row, const float* kwp, const float* kbp, int g,
    short (*kw)[72], short (*sQ)[40], float* sKB, int tid)
{
    *(bf16x8*)(&kw[tid >> 3][(tid & 7) * 8]) = cvt8(kwp + (size_t)g * 2048 + tid * 8);
    p2_stage_32x32(Y2row + 16384 + g * 1024, sQ, tid);
    if (tid < 32) sKB[tid] = kbp[g * 32 + tid];
}

// ---------------------------------------------------------------------------
// p2 split kernels (small-ws path)
// ---------------------------------------------------------------------------
__global__ __launch_bounds__(256) void p2_reg_kernel(
    const float* __restrict__ feats, const unsigned short* __restrict__ Y1,
    unsigned short* __restrict__ FMS)
{
    const int t = blockIdx.x, g = blockIdx.y;
    const int tid = threadIdx.x;
    __shared__ short fB[32][72];
    __shared__ short Mt[64][72];
    __shared__ short sS[32][40];
    __shared__ short X1T[64][40];
    __shared__ float sRed[16];

    p2_stage_feats(feats + (size_t)(t * NG + g) * 2048, fB, tid);
    p2_stage_64x64(Y1 + (size_t)t * 20480 + g * 4096, Mt, tid);
    p2_stage_32x32(Y1 + (size_t)t * 20480 + 16384 + g * 1024, sS, tid);
    __syncthreads();
    p2_reg_body(fB, Mt, sS, X1T, sRed, FMS + (size_t)t * 8192 + g * 2048, tid);
}

__global__ __launch_bounds__(256) void p2_cls_kernel(
    const float* __restrict__ feats, const unsigned short* __restrict__ Y2,
    const float* __restrict__ kwp, const float* __restrict__ kbp,
    unsigned short* __restrict__ FC)
{
    const int t = blockIdx.x, g = blockIdx.y;
    const int tid = threadIdx.x;
    __shared__ short fB[32][72];
    __shared__ short Vt[64][72];
    __shared__ short kw[32][72];
    __shared__ short vRM[32][72];
    __shared__ short vT[64][40];
    __shared__ short kT[32][40];
    __shared__ short sQ[32][40];
    __shared__ short sSC[32][40];
    __shared__ float sKB[32];
    __shared__ float sRed[16];

    p2_stage_feats(feats + (size_t)(t * NG + g) * 2048, fB, tid);
    p2_stage_64x64(Y2 + (size_t)t * 20480 + g * 4096, Vt, tid);
    p2_stage_cls(Y2 + (size_t)t * 20480, kwp, kbp, g, kw, sQ, sKB, tid);
    __syncthreads();
    p2_cls_body(fB, Vt, kw, vRM, vT, kT, sQ, sSC, sKB, sRed,
                FC + (size_t)t * 8192 + g * 2048, tid);
}

// ---------------------------------------------------------------------------
// p2 fused kernel (big-ws path) — R20 structure (82us proven), unchanged.
// ---------------------------------------------------------------------------
__global__ __launch_bounds__(256, 5) void p2_fused_kernel(
    const float* __restrict__ feats,
    const unsigned short* __restrict__ Y1,
    const unsigned short* __restrict__ Y2,
    const float* __restrict__ kwp, const float* __restrict__ kbp,
    unsigned short* __restrict__ FMS, unsigned short* __restrict__ FC)
{
    const int t = blockIdx.x, g = blockIdx.y;
    const int tid = threadIdx.x;
    const int wave = tid >> 6, lane = tid & 63;
    const int l16 = lane & 15, quad = lane >> 4;

    __shared__ short fB[32][72];     // feats ; then kw
    __shared__ short MtVt[64][72];   // M ; then V
    __shared__ short XvT[64][40];    // X1T ; then vT
    __shared__ short sSQ[32][40];    // S ; then Q
    __shared__ short vRM[32][72];    // v row-major ; then softmax scores
    __shared__ short kT[32][40];
    __shared__ float sKB[32];
    __shared__ float sRed[16];
    short (*sSC)[72] = vRM;          // alias: scores after vRM is dead

    // ---- issue ALL global loads up-front (T14, coalesced only) ----
    const float* fp = feats + (size_t)(t * NG + g) * 2048 + tid * 8;
    float4 f0 = ((const float4*)fp)[0];
    float4 f1 = ((const float4*)fp)[1];
    const unsigned short* y1m = Y1 + (size_t)t * 20480 + g * 4096 + tid * 16;
    bf16x8 m0 = ((const bf16x8*)y1m)[0];
    bf16x8 m1 = ((const bf16x8*)y1m)[1];
    bf16x4 s0 = *(const bf16x4*)(Y1 + (size_t)t * 20480 + 16384 + g * 1024 + tid * 4);
    const unsigned short* y2v = Y2 + (size_t)t * 20480 + g * 4096 + tid * 16;
    bf16x8 v0 = ((const bf16x8*)y2v)[0];
    bf16x8 v1 = ((const bf16x8*)y2v)[1];
    bf16x4 q0 = *(const bf16x4*)(Y2 + (size_t)t * 20480 + 16384 + g * 1024 + tid * 4);
    bf16x8 kwv = cvt8(kwp + (size_t)g * 2048 + tid * 8);
    float kbv = (tid < 32) ? kbp[g * 32 + tid] : 0.f;

    // ---- stage phase-1 LDS (anchors feats/M/S loads) ----
    {
        bf16x8 v;
        v[0]=(short)f2b(f0.x); v[1]=(short)f2b(f0.y); v[2]=(short)f2b(f0.z); v[3]=(short)f2b(f0.w);
        v[4]=(short)f2b(f1.x); v[5]=(short)f2b(f1.y); v[6]=(short)f2b(f1.z); v[7]=(short)f2b(f1.w);
        *(bf16x8*)(&fB[tid >> 3][(tid & 7) * 8]) = v;
    }
    {   // frag-major decode: element index r = 2*tid (+1), 8-elem runs
        const int r0 = 2 * tid, r1 = 2 * tid + 1;
        int ch = r0 >> 6, lf = r0 & 63;
        *(bf16x8*)(&MtVt[(ch >> 1) * 16 + (lf & 15)][(ch & 1) * 32 + (lf >> 4) * 8]) = m0;
        ch = r1 >> 6; lf = r1 & 63;
        *(bf16x8*)(&MtVt[(ch >> 1) * 16 + (lf & 15)][(ch & 1) * 32 + (lf >> 4) * 8]) = m1;
        // S: 4-elem runs; element index 4*tid
        const int cs = tid >> 7, lsn = (tid >> 1) & 63;
        *(bf16x4*)(&sSQ[cs * 16 + (lsn & 15)][(lsn >> 4) * 8 + (tid & 1) * 4]) = s0;
    }
    if (tid < 32) sKB[tid] = kbv;
    __syncthreads();

    unsigned short* outR = FMS + (size_t)t * 8192 + g * 2048;
    unsigned short* outC = FC  + (size_t)t * 8192 + g * 2048;
    float mean, istd, ls, lq;

    // ================= reg branch =================
    {
        f32x4 accA[2] = {};
        #pragma unroll
        for (int ks = 0; ks < 64; ks += 32) {
            bf16x8 b = *(const bf16x8*)(&MtVt[wave * 16 + l16][ks + quad * 8]);
            #pragma unroll
            for (int mt = 0; mt < 2; ++mt) {
                bf16x8 a = *(const bf16x8*)(&fB[mt * 16 + l16][ks + quad * 8]);
                accA[mt] = __builtin_amdgcn_mfma_f32_16x16x32_bf16(a, b, accA[mt], 0, 0, 0);
            }
        }
        ls = 0.f; lq = 0.f;
        #pragma unroll
        for (int mt = 0; mt < 2; ++mt)
            #pragma unroll
            for (int r = 0; r < 4; ++r) { float v = accA[mt][r]; ls += v; lq += v * v; }
        block_stats2(ls, lq, sRed, tid, 1.0f / 2048.0f, mean, istd);
        #pragma unroll
        for (int mt = 0; mt < 2; ++mt) {
            bf16x4 pk;
            #pragma unroll
            for (int r = 0; r < 4; ++r) {
                float y = (accA[mt][r] - mean) * istd;
                pk[r] = (short)f2b(y > 0.f ? y : 0.f);
            }
            *(bf16x4*)(&XvT[wave * 16 + l16][mt * 16 + quad * 4]) = pk;
        }
        __syncthreads();

        f32x4 accB[2] = {};
        {
            bf16x8 b = *(const bf16x8*)(&XvT[wave * 16 + l16][quad * 8]);
            #pragma unroll
            for (int mt = 0; mt < 2; ++mt) {
                bf16x8 a = *(const bf16x8*)(&sSQ[mt * 16 + l16][quad * 8]);
                accB[mt] = __builtin_amdgcn_mfma_f32_16x16x32_bf16(a, b, accB[mt], 0, 0, 0);
            }
        }
        ls = 0.f; lq = 0.f;
        #pragma unroll
        for (int mt = 0; mt < 2; ++mt)
            #pragma unroll
            for (int r = 0; r < 4; ++r) { float v = accB[mt][r]; ls += v; lq += v * v; }
        block_stats2(ls, lq, sRed, tid, 1.0f / 2048.0f, mean, istd);
        // after this barrier: MtVt and sSQ reads are done
        const int d = wave * 16 + l16;
        #pragma unroll
        for (int mt = 0; mt < 2; ++mt)
            #pragma unroll
            for (int r = 0; r < 4; ++r) {
                float y = (accB[mt][r] - mean) * istd;
                outR[(mt * 16 + quad * 4 + r) * 64 + d] = f2b(y > 0.f ? y : 0.f);
            }
    }

    // ---- stage phase-2 LDS from prefetched regs (no global latency) ----
    {
        const int r0 = 2 * tid, r1 = 2 * tid + 1;
        int ch = r0 >> 6, lf = r0 & 63;
        *(bf16x8*)(&MtVt[(ch >> 1) * 16 + (lf & 15)][(ch & 1) * 32 + (lf >> 4) * 8]) = v0;
        ch = r1 >> 6; lf = r1 & 63;
        *(bf16x8*)(&MtVt[(ch >> 1) * 16 + (lf & 15)][(ch & 1) * 32 + (lf >> 4) * 8]) = v1;
        const int cs = tid >> 7, lsn = (tid >> 1) & 63;
        *(bf16x4*)(&sSQ[cs * 16 + (lsn & 15)][(lsn >> 4) * 8 + (tid & 1) * 4]) = q0;
    }
    __syncthreads();

    // ================= cls branch =================
    {
        f32x4 accA[2] = {};
        #pragma unroll
        for (int ks = 0; ks < 64; ks += 32) {
            bf16x8 b = *(const bf16x8*)(&MtVt[wave * 16 + l16][ks + quad * 8]);
            #pragma unroll
            for (int mt = 0; mt < 2; ++mt) {
                bf16x8 a = *(const bf16x8*)(&fB[mt * 16 + l16][ks + quad * 8]);
                accA[mt] = __builtin_amdgcn_mfma_f32_16x16x32_bf16(a, b, accA[mt], 0, 0, 0);
            }
        }
        ls = 0.f; lq = 0.f;
        #pragma unroll
        for (int mt = 0; mt < 2; ++mt)
            #pragma unroll
            for (int r = 0; r < 4; ++r) { float v = accA[mt][r]; ls += v; lq += v * v; }
        block_stats2(ls, lq, sRed, tid, 1.0f / 2048.0f, mean, istd);
        // after barrier: all fB reads done -> safe to overwrite with kw below
        {
            const int d = wave * 16 + l16;
            #pragma unroll
            for (int mt = 0; mt < 2; ++mt) {
                bf16x4 pk;
                #pragma unroll
                for (int r = 0; r < 4; ++r) {
                    float y = (accA[mt][r] - mean) * istd;
                    unsigned short u = f2b(y > 0.f ? y : 0.f);
                    pk[r] = (short)u;
                    vRM[mt * 16 + quad * 4 + r][d] = (short)u;
                }
                *(bf16x4*)(&XvT[d][mt * 16 + quad * 4]) = pk;   // vT
            }
        }
        // stage kw into fB's space (from prefetched regs)
        *(bf16x8*)(&fB[tid >> 3][(tid & 7) * 8]) = kwv;
        __syncthreads();

        {   // k[i][p] = kw[i]·v[p] + kb
            const int it = wave >> 1, pt = wave & 1;
            f32x4 accK = {};
            #pragma unroll
            for (int ks = 0; ks < 64; ks += 32) {
                bf16x8 a = *(const bf16x8*)(&fB[it * 16 + l16][ks + quad * 8]);
                bf16x8 b = *(const bf16x8*)(&vRM[pt * 16 + l16][ks + quad * 8]);
                accK = __builtin_amdgcn_mfma_f32_16x16x32_bf16(a, b, accK, 0, 0, 0);
            }
            bf16x4 pk;
            #pragma unroll
            for (int r = 0; r < 4; ++r)
                pk[r] = (short)f2b(accK[r] + sKB[it * 16 + quad * 4 + r]);
            *(bf16x4*)(&kT[pt * 16 + l16][it * 16 + quad * 4]) = pk;
        }
        __syncthreads();
        // vRM dead from here; sSC (alias) becomes live

        if (wave < 2) {   // logits + softmax
            f32x4 accL[2] = {};
            bf16x8 a = *(const bf16x8*)(&sSQ[wave * 16 + l16][quad * 8]);
            #pragma unroll
            for (int pt = 0; pt < 2; ++pt) {
                bf16x8 b = *(const bf16x8*)(&kT[pt * 16 + l16][quad * 8]);
                accL[pt] = __builtin_amdgcn_mfma_f32_16x16x32_bf16(a, b, accL[pt], 0, 0, 0);
            }
            #pragma unroll
            for (int r = 0; r < 4; ++r) {
                float a0 = accL[0][r] * 0.125f, a1 = accL[1][r] * 0.125f;
                float mx = fmaxf(a0, a1);
                #pragma unroll
                for (int m = 1; m < 16; m <<= 1) mx = fmaxf(mx, __shfl_xor(mx, m, 64));
                a0 = __expf(a0 - mx); a1 = __expf(a1 - mx);
                float sum = a0 + a1;
                #pragma unroll
                for (int m = 1; m < 16; m <<= 1) sum += __shfl_xor(sum, m, 64);
                const float inv_s = 1.0f / sum;
                const int o = wave * 16 + quad * 4 + r;
                sSC[o][l16]      = (short)f2b(a0 * inv_s);
                sSC[o][16 + l16] = (short)f2b(a1 * inv_s);
            }
        }
        __syncthreads();

        f32x4 accB[2] = {};
        {
            bf16x8 b = *(const bf16x8*)(&XvT[wave * 16 + l16][quad * 8]);
            #pragma unroll
            for (int mt = 0; mt < 2; ++mt) {
                bf16x8 a = *(const bf16x8*)(&sSC[mt * 16 + l16][quad * 8]);
                accB[mt] = __builtin_amdgcn_mfma_f32_16x16x32_bf16(a, b, accB[mt], 0, 0, 0);
            }
        }
        ls = 0.f; lq = 0.f;
        #pragma unroll
        for (int mt = 0; mt < 2; ++mt)
            #pragma unroll
            for (int r = 0; r < 4; ++r) { float v = accB[mt][r]; ls += v; lq += v * v; }
        block_stats2(ls, lq, sRed, tid, 1.0f / 2048.0f, mean, istd);

        const int d = wave * 16 + l16;
        #pragma unroll
        for (int mt = 0; mt < 2; ++mt)
            #pragma unroll
            for (int r = 0; r < 4; ++r) {
                float y = (accB[mt][r] - mean) * istd;
                outC[(mt * 16 + quad * 4 + r) * 64 + d] = f2b(y > 0.f ? y : 0.f);
            }
    }
}

// ---------------------------------------------------------------------------
// Final: reduce split-K=8 partials, residual add, affine LN over 256, fp32 out.
// ---------------------------------------------------------------------------
__global__ __launch_bounds__(256) void final_ln_kernel(
    const float* __restrict__ qv,
    const float* __restrict__ MSP, const float* __restrict__ CLP,
    const float* __restrict__ Wv_b, const float* __restrict__ Wv2_b,
    const float* __restrict__ lnA_w, const float* __restrict__ lnA_b,
    const float* __restrict__ lnB_w, const float* __restrict__ lnB_b,
    float* __restrict__ out)
{
    __shared__ float sRed[16];
    const int t = blockIdx.x;
    const int br = blockIdx.y;
    const int c = threadIdx.x;
    const float* P = br ? CLP : MSP;
    const float* bias = br ? Wv2_b : Wv_b;
    const float* lw = br ? lnB_w : lnA_w;
    const float* lb = br ? lnB_b : lnA_b;

    float x = qv[t * 256 + c] + bias[c];
    #pragma unroll
    for (int s = 0; s < 8; ++s) x += P[(size_t)s * (BN * 256) + t * 256 + c];

    float mean, istd;
    block_stats(x, x * x, sRed, c, 1.0f / 256.0f, mean, istd);
    out[(size_t)br * (BN * 256) + t * 256 + c] = (x - mean) * istd * lw[c] + lb[c];
}

// ---------------------------------------------------------------------------
extern "C" void kernel_launch(void* const* d_in, const int* in_sizes, int n_in,
                              void* d_out, int out_size, void* d_ws, size_t ws_size,
                              hipStream_t stream) {
    const float* feats = (const float*)d_in[0];
    const float* qv    = (const float*)d_in[1];
    const float* m_w   = (const float*)d_in[7];
    const float* m_b   = (const float*)d_in[8];
    const float* s_w   = (const float*)d_in[9];
    const float* s_b   = (const float*)d_in[10];
    const float* q_w   = (const float*)d_in[11];
    const float* q_b   = (const float*)d_in[12];
    const float* v_w   = (const float*)d_in[13];
    const float* v_b   = (const float*)d_in[14];
    const float* k_w   = (const float*)d_in[15];
    const float* k_b   = (const float*)d_in[16];
    const float* Wv_w  = (const float*)d_in[17];
    const float* Wv_b  = (const float*)d_in[18];
    const float* Wv2_w = (const float*)d_in[19];
    const float* Wv2_b = (const float*)d_in[20];
    const float* lnA_w = (const float*)d_in[21];
    const float* lnA_b = (const float*)d_in[22];
    const float* lnB_w = (const float*)d_in[23];
    const float* lnB_b = (const float*)d_in[24];

    char* ws = (char*)d_ws;
    const dim3 blk(256);

    if (ws_size >= 275251200ull) {
        // ===== BIG path (275.3 MB) =====
        unsigned short* Y1 = (unsigned short*)(ws);
        unsigned short* Y2 = (unsigned short*)(ws + 98304000);
        unsigned short* W1   = (unsigned short*)(ws + 196608000);
        unsigned short* W2   = (unsigned short*)(ws + 196608000 + 10485760);
        unsigned short* qvP  = (unsigned short*)(ws + 196608000 + 20971520);
        float* b1 = (float*)(ws + 196608000 + 22216704);
        float* b2 = (float*)(ws + 196608000 + 22298624);
        unsigned short* FMS = (unsigned short*)(ws + 196608000);
        unsigned short* FC  = (unsigned short*)(ws + 235929600);
        unsigned short* WvB  = (unsigned short*)(ws + 98304000);
        unsigned short* Wv2B = (unsigned short*)(ws + 98304000 + 4194304);
        float* MSP = (float*)(ws);
        float* CLP = (float*)(ws + 19660800);

        prep_perm_kernel<<<dim3(4096, 2), blk, 0, stream>>>(m_w, m_b, W1, b1,
                                                            v_w, v_b, W2, b2);
        prep_flat_frag_kernel<<<dim3(512, 2), blk, 0, stream>>>(s_w, W1, q_w, W2);
        prep_pack_a_kernel<<<304, blk, 0, stream>>>(qv, qvP);
        copy_bias_kernel<<<dim3(16, 2), blk, 0, stream>>>(s_b, b1 + 16384, q_b, b2 + 16384);
        gemm_gen_kernel<<<dim3(19, 320), blk, 0, stream>>>(
            qvP, W1, b1, Y1, W2, b2, Y2, 160, BN, 20480);
        p2_fused_kernel<<<dim3(BN, NG), blk, 0, stream>>>(
            feats, Y1, Y2, k_w, k_b, FMS, FC);
        prep_projw_kernel<<<dim3(1024, 2), blk, 0, stream>>>(Wv_w, WvB, Wv2_w, Wv2B);
        gemm_proj_kernel<<<dim3(38, 16), blk, 0, stream>>>(
            FMS, WvB, MSP, FC, Wv2B, CLP, 8, BN, 256, 8192, 1024);
        final_ln_kernel<<<dim3(BN, 2), blk, 0, stream>>>(
            qv, MSP, CLP, Wv_b, Wv2_b, lnA_w, lnA_b, lnB_w, lnB_b, (float*)d_out);
    } else {
        // ===== SMALL path (176.9 MB fallback) =====
        unsigned short* Y1  = (unsigned short*)(ws);
        unsigned short* FMS = (unsigned short*)(ws + 98304000);
        unsigned short* FC  = (unsigned short*)(ws + 137625600);
        unsigned short* W1   = (unsigned short*)(ws + 137625600);
        unsigned short* W2   = (unsigned short*)(ws + 137625600 + 10485760);
        unsigned short* qvP  = (unsigned short*)(ws + 137625600 + 20971520);
        float* b1 = (float*)(ws + 137625600 + 22216704);
        float* b2 = (float*)(ws + 137625600 + 22298624);
        float* MSP = (float*)(ws);
        float* CLP = (float*)(ws + 19660800);
        unsigned short* WvB  = (unsigned short*)(ws + 39321600);
        unsigned short* Wv2B = (unsigned short*)(ws + 43515904);

        prep_perm_kernel<<<dim3(4096, 2), blk, 0, stream>>>(m_w, m_b, W1, b1,
                                                            v_w, v_b, W2, b2);
        prep_flat_frag_kernel<<<dim3(512, 2), blk, 0, stream>>>(s_w, W1, q_w, W2);
        prep_pack_a_kernel<<<304, blk, 0, stream>>>(qv, qvP);
        copy_bias_kernel<<<dim3(16, 2), blk, 0, stream>>>(s_b, b1 + 16384, q_b, b2 + 16384);
        gemm_gen_kernel<<<dim3(19, 160), blk, 0, stream>>>(
            qvP, W1, b1, Y1, W1, b1, Y1, 160, BN, 20480);
        p2_reg_kernel<<<dim3(BN, NG), blk, 0, stream>>>(feats, Y1, FMS);
        gemm_gen_kernel<<<dim3(19, 160), blk, 0, stream>>>(
            qvP, W2, b2, Y1, W2, b2, Y1, 160, BN, 20480);
        p2_cls_kernel<<<dim3(BN, NG), blk, 0, stream>>>(feats, Y1, k_w, k_b, FC);
        prep_projw_kernel<<<dim3(1024, 2), blk, 0, stream>>>(Wv_w, WvB, Wv2_w, Wv2B);
        gemm_proj_kernel<<<dim3(38, 8), blk, 0, stream>>>(
            FMS, WvB, MSP, FMS, WvB, MSP, 8, BN, 256, 8192, 1024);
        gemm_proj_kernel<<<dim3(38, 8), blk, 0, stream>>>(
            FC, Wv2B, CLP, FC, Wv2B, CLP, 8, BN, 256, 8192, 1024);
        final_ln_kernel<<<dim3(BN, 2), blk, 0, stream>>>(
            qv, MSP, CLP, Wv_b, Wv2_b, lnA_w, lnA_b, lnB_w, lnB_b, (float*)d_out);
    }
}